// Round 9
// baseline (412.964 us; speedup 1.0000x reference)
//
#include <hip/hip_runtime.h>
#include <hip/hip_bf16.h>
#include <stdint.h>

#define S 4096
#define E 512
#define H 8
#define D 64
#define MROW 5000        // mask row stride (MAX_GENES)

typedef __hip_bfloat16 bf16;
typedef __attribute__((ext_vector_type(8))) short bf16x8;
typedef __attribute__((ext_vector_type(4))) float f32x4;

#define CMUL (0.125f * 1.4426950408889634f)  // scale * log2(e), folded into Q

union u4bf8 { uint4 u; bf16x8 b; };

// ---------------------------------------------------------------------------
// Mask dtype sniffer (parallel, 1 wave). flag[1]=1 if byte-packed bool.
// ---------------------------------------------------------------------------
__global__ void sniff(const unsigned int* __restrict__ mask,
                      int* __restrict__ flag)
{
    int lane = threadIdx.x & 63;
    int hit = 0;
    for (int i = lane; i < 2048; i += 64) {
        unsigned int w = mask[i];
        if (w > 1u && (w & 0xFEFEFEFEu) == 0u) hit = 1;
    }
    unsigned long long b = __ballot(hit);
    if (lane == 0) { flag[1] = (b != 0ull) ? 1 : 0; flag[0] = 1; }
}

// ---------------------------------------------------------------------------
// Convert fp32 params into canonical bf16 buffers.
// ---------------------------------------------------------------------------
__global__ __launch_bounds__(256) void convert_all(
    const float* __restrict__ x,  const float* __restrict__ wq,
    const float* __restrict__ wk, const float* __restrict__ wv,
    const float* __restrict__ wo, const float* __restrict__ bq,
    const float* __restrict__ bk, const float* __restrict__ bv,
    const float* __restrict__ bo,
    bf16* __restrict__ xb, bf16* __restrict__ wcat, bf16* __restrict__ wob,
    bf16* __restrict__ bcat, bf16* __restrict__ bob)
{
    const float* srcs[9] = {x, wq, wk, wv, wo, bq, bk, bv, bo};
    bf16* dsts[9] = {xb, wcat, wcat + 262144, wcat + 524288, wob,
                     bcat, bcat + 512, bcat + 1024, bob};
    const int cnts[9] = {2097152, 262144, 262144, 262144, 262144,
                         512, 512, 512, 512};
    const int ngroups = (2097152 + 4 * 262144 + 4 * 512) / 4;
    for (int g = blockIdx.x * blockDim.x + threadIdx.x; g < ngroups;
         g += gridDim.x * blockDim.x) {
        int e = g * 4;
        int seg = 0;
        while (e >= cnts[seg]) { e -= cnts[seg]; ++seg; }
        float4 v = *(const float4*)(srcs[seg] + e);
        union { bf16 h[4]; uint2 u; } cv;
        cv.h[0] = (bf16)v.x; cv.h[1] = (bf16)v.y;
        cv.h[2] = (bf16)v.z; cv.h[3] = (bf16)v.w;
        *(uint2*)(dsts[seg] + e) = cv.u;
    }
}

// ---------------------------------------------------------------------------
// Pack mask into bit matrix bits[row][word] for the 4096x4096 region.
// ---------------------------------------------------------------------------
__global__ __launch_bounds__(256) void pack_mask(const void* __restrict__ mask,
                                                 unsigned long long* __restrict__ bits,
                                                 const int* __restrict__ flag)
{
    const bool isbyte = flag[1] != 0;
    int wid   = (blockIdx.x * blockDim.x + threadIdx.x) >> 6;
    int lane  = threadIdx.x & 63;
    int nwav  = (gridDim.x * blockDim.x) >> 6;
    int total = S * (S / 64);
    for (int w = wid; w < total; w += nwav) {
        int row  = w >> 6;
        int word = w & 63;
        int col  = word * 64 + lane;
        unsigned int v;
        if (isbyte) v = ((const unsigned char*)mask)[(size_t)row * MROW + col];
        else        v = ((const unsigned int*)mask)[(size_t)row * MROW + col];
        unsigned long long b = __ballot(v != 0u);
        if (lane == 0) bits[(size_t)row * 64 + word] = b;
    }
}

// ---------------------------------------------------------------------------
// C(64x64 tile) = A(Mx512) @ W^T + bias.
// mode 0: QKV fused (N=1536); out planar Q|K|V, Q pre-scaled by CMUL.
// mode 1: out row-major [s][512] fp32 (final projection).
// ---------------------------------------------------------------------------
__global__ __launch_bounds__(256) void gemm64(const bf16* __restrict__ A,
                                              const bf16* __restrict__ W,
                                              const bf16* __restrict__ bias,
                                              void* __restrict__ outv, int mode)
{
    __shared__ bf16 As[64][72];
    __shared__ bf16 Bs[64][72];
    const int tid  = threadIdx.x;
    const int wid  = tid >> 6, lane = tid & 63;
    const int quad = lane >> 4, l15 = lane & 15;
    const int nbase = blockIdx.x * 64;
    const int mbase = blockIdx.y * 64;
    const int m0 = wid * 16;

    f32x4 acc[4];
#pragma unroll
    for (int i = 0; i < 4; ++i) acc[i] = (f32x4){0.f, 0.f, 0.f, 0.f};

    for (int kt = 0; kt < E / 64; ++kt) {
        const int kb = kt * 64;
        __syncthreads();
#pragma unroll
        for (int i = 0; i < 2; ++i) {
            int slot = tid + i * 256;
            int row = slot >> 3, kg = slot & 7;
            *(uint4*)&As[row][kg * 8] = *(const uint4*)&A[(size_t)(mbase + row) * E + kb + kg * 8];
            *(uint4*)&Bs[row][kg * 8] = *(const uint4*)&W[(size_t)(nbase + row) * E + kb + kg * 8];
        }
        __syncthreads();
        bf16x8 a0 = *(bf16x8*)&As[m0 + l15][quad * 8];
        bf16x8 a1 = *(bf16x8*)&As[m0 + l15][32 + quad * 8];
#pragma unroll
        for (int nt = 0; nt < 4; ++nt) {
            bf16x8 b0 = *(bf16x8*)&Bs[nt * 16 + l15][quad * 8];
            bf16x8 b1 = *(bf16x8*)&Bs[nt * 16 + l15][32 + quad * 8];
            acc[nt] = __builtin_amdgcn_mfma_f32_16x16x32_bf16(a0, b0, acc[nt], 0, 0, 0);
            acc[nt] = __builtin_amdgcn_mfma_f32_16x16x32_bf16(a1, b1, acc[nt], 0, 0, 0);
        }
    }
#pragma unroll
    for (int nt = 0; nt < 4; ++nt) {
        int col = nbase + nt * 16 + l15;
        float bv = (float)bias[col];
#pragma unroll
        for (int r = 0; r < 4; ++r) {
            int row = mbase + m0 + quad * 4 + r;
            float v = acc[nt][r] + bv;
            if (mode == 0) {
                int t = col >> 9, hh = (col >> 6) & 7, d = col & 63;
                if (t == 0) v *= CMUL;
                ((bf16*)outv)[((size_t)t * H + hh) * S * D + (size_t)row * D + d] = (bf16)v;
            } else {
                ((float*)outv)[(size_t)row * E + col] = v;
            }
        }
    }
}

// ---------------------------------------------------------------------------
// Fused flash attention. 256-thread blocks (4 waves), Q-tile 64, K-tile 64.
// K fragments loaded DIRECTLY from global (L2-resident, row-contiguous) — no
// K LDS, no K staging. V transposed through double-buffered LDS (one barrier
// per iteration). Ps aliases Qs. exp2-domain fixed softmax, K-split.
// grid: (S/64, H, nsplit).
// ---------------------------------------------------------------------------
__global__ __launch_bounds__(256) void attn(const bf16* __restrict__ Qp,
                                            const bf16* __restrict__ Kp,
                                            const bf16* __restrict__ Vp,
                                            const unsigned long long* __restrict__ bits,
                                            float* __restrict__ Opart,
                                            float* __restrict__ Lpart,
                                            int ktper)
{
    __shared__ __align__(16) char smem[25600];
    bf16 (*Qs)[72]     = (bf16(*)[72])smem;                 // 64x72 (9216 B)
    bf16 (*Ps)[16][64] = (bf16(*)[16][64])smem;             // aliases Qs after use
    bf16 (*Vts)[64][64] = (bf16(*)[64][64])(smem + 9216);   // 2 x 64x64 swizzled V^T

    const int tid  = threadIdx.x;
    const int wid  = tid >> 6, lane = tid & 63;
    const int quad = lane >> 4, l15 = lane & 15;
    const int qt = blockIdx.x, h = blockIdx.y, split = blockIdx.z;
    const int qbase = qt * 64;
    const int m0 = wid * 16;
    const bf16* Qh = Qp + (size_t)h * S * D;
    const bf16* Kh = Kp + (size_t)h * S * D;
    const bf16* Vh = Vp + (size_t)h * S * D;

    // V staging: 2 tokens x 8 dims/thread; swizzled col = vt0 ^ (j*8)
    const int vt0 = (tid & 31) * 2, vd0 = (tid >> 5) * 8;

    // stage Q once
#pragma unroll
    for (int i = 0; i < 2; ++i) {
        int slot = tid + i * 256;
        int row = slot >> 3, kg = slot & 7;
        *(uint4*)&Qs[row][kg * 8] = *(const uint4*)&Qh[(size_t)(qbase + row) * D + kg * 8];
    }
    __syncthreads();
    bf16x8 aq0 = *(bf16x8*)&Qs[m0 + l15][quad * 8];
    bf16x8 aq1 = *(bf16x8*)&Qs[m0 + l15][32 + quad * 8];

    // ones B-fragment for l-sum MFMA (col 0 only)
    bf16x8 bl;
    {
        union { short s; bf16 b; } one; one.b = (bf16)1.0f;
        short v = (l15 == 0) ? one.s : (short)0;
#pragma unroll
        for (int j = 0; j < 8; ++j) bl[j] = v;
    }

    f32x4 o[4];
#pragma unroll
    for (int dt = 0; dt < 4; ++dt) o[dt] = (f32x4){0.f, 0.f, 0.f, 0.f};
    f32x4 accl = (f32x4){0.f, 0.f, 0.f, 0.f};

    const int kt0 = split * ktper, kt1 = kt0 + ktper;

    // prefetch V tile kt0 into registers
    uint4 vq0, vq1;
    {
        const int kbase = kt0 * 64;
        vq0 = *(const uint4*)&Vh[(size_t)(kbase + vt0) * D + vd0];
        vq1 = *(const uint4*)&Vh[(size_t)(kbase + vt0 + 1) * D + vd0];
    }

    const int ksw_rd = (l15 & 7);               // Vts read swizzle key
    const int pkey   = ((l15 >> 1) & 7);        // Ps read swizzle key

#pragma unroll 1
    for (int kt = kt0; kt < kt1; ++kt) {
        const int kbase = kt * 64;
        const int buf = kt & 1;

        // issue K fragment loads for THIS tile (drain across V-store+barrier)
        u4bf8 kf[8];
        {
            const bf16* Kt = Kh + (size_t)kbase * D;
#pragma unroll
            for (int nt = 0; nt < 4; ++nt) {
                kf[nt * 2 + 0].u = *(const uint4*)&Kt[(nt * 16 + l15) * D + quad * 8];
                kf[nt * 2 + 1].u = *(const uint4*)&Kt[(nt * 16 + l15) * D + 32 + quad * 8];
            }
        }
        // V prefetch regs (tile kt) -> LDS buf
        {
            const unsigned short* p0 = (const unsigned short*)&vq0;
            const unsigned short* p1 = (const unsigned short*)&vq1;
#pragma unroll
            for (int j = 0; j < 8; ++j) {
                unsigned int pk = (unsigned int)p0[j] | ((unsigned int)p1[j] << 16);
                *(unsigned int*)&Vts[buf][vd0 + j][vt0 ^ (j * 8)] = pk;
            }
        }
        // prefetch V tile kt+1
        if (kt + 1 < kt1) {
            const int kb2 = (kt + 1) * 64;
            vq0 = *(const uint4*)&Vh[(size_t)(kb2 + vt0) * D + vd0];
            vq1 = *(const uint4*)&Vh[(size_t)(kb2 + vt0 + 1) * D + vd0];
        }
        // mask words
        unsigned long long mw[4];
#pragma unroll
        for (int r = 0; r < 4; ++r) {
            int row = qbase + m0 + quad * 4 + r;
            mw[r] = bits[(size_t)row * 64 + kt];
        }
        __syncthreads();   // V tile in buf visible to all waves

        // S = (Q*CMUL) K^T  (exp2 domain); K frags straight from global regs
        f32x4 sc[4];
        {
            f32x4 z = (f32x4){0.f, 0.f, 0.f, 0.f};
#pragma unroll
            for (int nt = 0; nt < 4; ++nt) {
                sc[nt] = __builtin_amdgcn_mfma_f32_16x16x32_bf16(aq0, kf[nt * 2 + 0].b, z, 0, 0, 0);
                sc[nt] = __builtin_amdgcn_mfma_f32_16x16x32_bf16(aq1, kf[nt * 2 + 1].b, sc[nt], 0, 0, 0);
            }
        }
        // p = exp2(s), masked -> 0; write swizzled P tile (wave-private)
#pragma unroll
        for (int r = 0; r < 4; ++r) {
            unsigned long long sh = mw[r] >> l15;
            int row = quad * 4 + r;
            int key = ((row >> 1) & 7) << 3;
#pragma unroll
            for (int nt = 0; nt < 4; ++nt) {
                float p = __builtin_amdgcn_exp2f(sc[nt][r]);
                bool ok = (sh >> (nt * 16)) & 1ull;
                p = ok ? p : 0.f;
                Ps[wid][row][(nt * 16 + l15) ^ key] = (bf16)p;
            }
        }
        // O += P V ; l += P 1
        bf16x8 ap0 = *(bf16x8*)&Ps[wid][l15][(quad ^ pkey) * 8];
        bf16x8 ap1 = *(bf16x8*)&Ps[wid][l15][((quad + 4) ^ pkey) * 8];
        accl = __builtin_amdgcn_mfma_f32_16x16x32_bf16(ap0, bl, accl, 0, 0, 0);
        accl = __builtin_amdgcn_mfma_f32_16x16x32_bf16(ap1, bl, accl, 0, 0, 0);
#pragma unroll
        for (int dt = 0; dt < 4; ++dt) {
            bf16x8 bv0 = *(bf16x8*)&Vts[buf][dt * 16 + l15][(quad ^ ksw_rd) * 8];
            bf16x8 bv1 = *(bf16x8*)&Vts[buf][dt * 16 + l15][((quad + 4) ^ ksw_rd) * 8];
            o[dt] = __builtin_amdgcn_mfma_f32_16x16x32_bf16(ap0, bv0, o[dt], 0, 0, 0);
            o[dt] = __builtin_amdgcn_mfma_f32_16x16x32_bf16(ap1, bv1, o[dt], 0, 0, 0);
        }
    }
    // epilogue: store fp32 partials; l lives in lanes l15==0 (col 0 of accl)
    float* Op = Opart + (size_t)(split * H + h) * S * D;
    float* Lp = Lpart + (size_t)(split * H + h) * S;
#pragma unroll
    for (int r = 0; r < 4; ++r) {
        int row = qbase + m0 + quad * 4 + r;
        if (l15 == 0) Lp[row] = accl[r];
#pragma unroll
        for (int dt = 0; dt < 4; ++dt)
            Op[(size_t)row * D + dt * 16 + l15] = o[dt][r];
    }
}

// ---------------------------------------------------------------------------
// Combine K-split partials: Ow[s][h*64+d] = sum_s Opart / sum_s Lpart (bf16).
// ---------------------------------------------------------------------------
__global__ __launch_bounds__(256) void combine(const float* __restrict__ Opart,
                                               const float* __restrict__ Lpart,
                                               bf16* __restrict__ Ow, int nsplit)
{
    int g = blockIdx.x * 256 + threadIdx.x;
    int e = g * 4;
    int row = e >> 9;
    int c = e & 511;
    int h = c >> 6, d = c & 63;
    size_t base = ((size_t)h * S + row) * D + d;
    const size_t oh = (size_t)H * S * D;
    float ax = 0.f, ay = 0.f, az = 0.f, aw = 0.f, l = 0.f;
    for (int s = 0; s < nsplit; ++s) {
        float4 a = *(const float4*)(Opart + (size_t)s * oh + base);
        ax += a.x; ay += a.y; az += a.z; aw += a.w;
        l += Lpart[(size_t)s * H * S + (size_t)h * S + row];
    }
    float inv = (l > 0.f) ? 1.f / l : 0.f;
    union { bf16 x[4]; uint2 u; } ov;
    ov.x[0] = (bf16)(ax * inv);
    ov.x[1] = (bf16)(ay * inv);
    ov.x[2] = (bf16)(az * inv);
    ov.x[3] = (bf16)(aw * inv);
    *(uint2*)(Ow + (size_t)row * E + c) = ov.u;
}

// ---------------------------------------------------------------------------
extern "C" void kernel_launch(void* const* d_in, const int* in_sizes, int n_in,
                              void* d_out, int out_size, void* d_ws, size_t ws_size,
                              hipStream_t stream)
{
    char* ws = (char*)d_ws;
    const size_t MB = (size_t)1 << 20;
    bf16* Qw   = (bf16*)(ws + 0 * MB);        // 12 MB: Q|K|V planar cat
    bf16* Kw   = (bf16*)(ws + 4 * MB);
    bf16* Vw   = (bf16*)(ws + 8 * MB);
    bf16* Ow   = (bf16*)(ws + 12 * MB);       // 4 MB [s][512] bf16
    unsigned long long* bits = (unsigned long long*)(ws + 16 * MB); // 2 MB
    bf16* xb   = (bf16*)(ws + 18 * MB);       // 4 MB
    bf16* Wcat = (bf16*)(ws + 22 * MB);       // 1.5 MB
    bf16* Wob  = (bf16*)(ws + 24 * MB);       // 0.5 MB
    bf16* bcat = (bf16*)(ws + 25 * MB);
    bf16* bob  = (bf16*)(ws + 25 * MB + 8192);
    int*  flag = (int*)(ws + 25 * MB + 16384);
    float* Opart = (float*)(ws + 26 * MB);    // nsplit x 8 MB

    int nsplit = (ws_size >= 59 * MB) ? 4 : 2;
    int ktper  = (S / 64) / nsplit;
    float* Lpart = (float*)(ws + 26 * MB + (size_t)nsplit * 8 * MB);

    hipLaunchKernelGGL(sniff, dim3(1), dim3(64), 0, stream,
                       (const unsigned int*)d_in[9], flag);
    hipLaunchKernelGGL(convert_all, dim3(1024), dim3(256), 0, stream,
                       (const float*)d_in[0], (const float*)d_in[1],
                       (const float*)d_in[3], (const float*)d_in[5],
                       (const float*)d_in[7], (const float*)d_in[2],
                       (const float*)d_in[4], (const float*)d_in[6],
                       (const float*)d_in[8],
                       xb, Wcat, Wob, bcat, bob);
    hipLaunchKernelGGL(pack_mask, dim3(1024), dim3(256), 0, stream, d_in[9], bits, flag);
    hipLaunchKernelGGL(gemm64, dim3(24, 64), dim3(256), 0, stream, xb, Wcat, bcat, (void*)Qw, 0);
    hipLaunchKernelGGL(attn, dim3(S / 64, H, nsplit), dim3(256), 0, stream,
                       Qw, Kw, Vw, bits, Opart, Lpart, ktper);
    hipLaunchKernelGGL(combine, dim3(2048), dim3(256), 0, stream, Opart, Lpart, Ow, nsplit);
    hipLaunchKernelGGL(gemm64, dim3(8, 64), dim3(256), 0, stream, Ow, Wob, bob, d_out, 1);
}

// Round 10
// 409.873 us; speedup vs baseline: 1.0075x; 1.0075x over previous
//
#include <hip/hip_runtime.h>
#include <hip/hip_bf16.h>
#include <stdint.h>

#define S 4096
#define E 512
#define H 8
#define D 64
#define MROW 5000        // mask row stride (MAX_GENES)

typedef __hip_bfloat16 bf16;
typedef __attribute__((ext_vector_type(8))) short bf16x8;
typedef __attribute__((ext_vector_type(4))) float f32x4;

#define CMUL (0.125f * 1.4426950408889634f)  // scale * log2(e), folded into Q

union u4bf8 { uint4 u; bf16x8 b; };

// ---------------------------------------------------------------------------
// Mask dtype sniffer (parallel, 1 wave). flag[1]=1 if byte-packed bool.
// ---------------------------------------------------------------------------
__global__ void sniff(const unsigned int* __restrict__ mask,
                      int* __restrict__ flag)
{
    int lane = threadIdx.x & 63;
    int hit = 0;
    for (int i = lane; i < 2048; i += 64) {
        unsigned int w = mask[i];
        if (w > 1u && (w & 0xFEFEFEFEu) == 0u) hit = 1;
    }
    unsigned long long b = __ballot(hit);
    if (lane == 0) { flag[1] = (b != 0ull) ? 1 : 0; flag[0] = 1; }
}

// ---------------------------------------------------------------------------
// Convert fp32 params into canonical bf16 buffers.
// ---------------------------------------------------------------------------
__global__ __launch_bounds__(256) void convert_all(
    const float* __restrict__ x,  const float* __restrict__ wq,
    const float* __restrict__ wk, const float* __restrict__ wv,
    const float* __restrict__ wo, const float* __restrict__ bq,
    const float* __restrict__ bk, const float* __restrict__ bv,
    const float* __restrict__ bo,
    bf16* __restrict__ xb, bf16* __restrict__ wcat, bf16* __restrict__ wob,
    bf16* __restrict__ bcat, bf16* __restrict__ bob)
{
    const float* srcs[9] = {x, wq, wk, wv, wo, bq, bk, bv, bo};
    bf16* dsts[9] = {xb, wcat, wcat + 262144, wcat + 524288, wob,
                     bcat, bcat + 512, bcat + 1024, bob};
    const int cnts[9] = {2097152, 262144, 262144, 262144, 262144,
                         512, 512, 512, 512};
    const int ngroups = (2097152 + 4 * 262144 + 4 * 512) / 4;
    for (int g = blockIdx.x * blockDim.x + threadIdx.x; g < ngroups;
         g += gridDim.x * blockDim.x) {
        int e = g * 4;
        int seg = 0;
        while (e >= cnts[seg]) { e -= cnts[seg]; ++seg; }
        float4 v = *(const float4*)(srcs[seg] + e);
        union { bf16 h[4]; uint2 u; } cv;
        cv.h[0] = (bf16)v.x; cv.h[1] = (bf16)v.y;
        cv.h[2] = (bf16)v.z; cv.h[3] = (bf16)v.w;
        *(uint2*)(dsts[seg] + e) = cv.u;
    }
}

// ---------------------------------------------------------------------------
// Pack mask into TRANSPOSED bit matrix bitsT[word][row] (word=token-tile col
// group, row=query row). Write side coalesced: consecutive waves, same word,
// consecutive rows -> 8B-stride writes.
// ---------------------------------------------------------------------------
__global__ __launch_bounds__(256) void pack_mask(const void* __restrict__ mask,
                                                 unsigned long long* __restrict__ bitsT,
                                                 const int* __restrict__ flag)
{
    const bool isbyte = flag[1] != 0;
    int wid   = (blockIdx.x * blockDim.x + threadIdx.x) >> 6;
    int lane  = threadIdx.x & 63;
    int nwav  = (gridDim.x * blockDim.x) >> 6;
    int total = (S / 64) * S;
    for (int w = wid; w < total; w += nwav) {
        int word = w >> 12;          // 0..63
        int row  = w & (S - 1);      // 0..4095
        int col  = word * 64 + lane;
        unsigned int v;
        if (isbyte) v = ((const unsigned char*)mask)[(size_t)row * MROW + col];
        else        v = ((const unsigned int*)mask)[(size_t)row * MROW + col];
        unsigned long long b = __ballot(v != 0u);
        if (lane == 0) bitsT[(size_t)word * S + row] = b;
    }
}

// ---------------------------------------------------------------------------
// C(64x64 tile) = A(Mx512) @ W^T + bias.
// mode 0: QKV fused (N=1536); out planar Q|K|V, Q pre-scaled by CMUL.
// mode 1: out row-major [s][512] fp32 (final projection).
// ---------------------------------------------------------------------------
__global__ __launch_bounds__(256) void gemm64(const bf16* __restrict__ A,
                                              const bf16* __restrict__ W,
                                              const bf16* __restrict__ bias,
                                              void* __restrict__ outv, int mode)
{
    __shared__ bf16 As[64][72];
    __shared__ bf16 Bs[64][72];
    const int tid  = threadIdx.x;
    const int wid  = tid >> 6, lane = tid & 63;
    const int quad = lane >> 4, l15 = lane & 15;
    const int nbase = blockIdx.x * 64;
    const int mbase = blockIdx.y * 64;
    const int m0 = wid * 16;

    f32x4 acc[4];
#pragma unroll
    for (int i = 0; i < 4; ++i) acc[i] = (f32x4){0.f, 0.f, 0.f, 0.f};

    for (int kt = 0; kt < E / 64; ++kt) {
        const int kb = kt * 64;
        __syncthreads();
#pragma unroll
        for (int i = 0; i < 2; ++i) {
            int slot = tid + i * 256;
            int row = slot >> 3, kg = slot & 7;
            *(uint4*)&As[row][kg * 8] = *(const uint4*)&A[(size_t)(mbase + row) * E + kb + kg * 8];
            *(uint4*)&Bs[row][kg * 8] = *(const uint4*)&W[(size_t)(nbase + row) * E + kb + kg * 8];
        }
        __syncthreads();
        bf16x8 a0 = *(bf16x8*)&As[m0 + l15][quad * 8];
        bf16x8 a1 = *(bf16x8*)&As[m0 + l15][32 + quad * 8];
#pragma unroll
        for (int nt = 0; nt < 4; ++nt) {
            bf16x8 b0 = *(bf16x8*)&Bs[nt * 16 + l15][quad * 8];
            bf16x8 b1 = *(bf16x8*)&Bs[nt * 16 + l15][32 + quad * 8];
            acc[nt] = __builtin_amdgcn_mfma_f32_16x16x32_bf16(a0, b0, acc[nt], 0, 0, 0);
            acc[nt] = __builtin_amdgcn_mfma_f32_16x16x32_bf16(a1, b1, acc[nt], 0, 0, 0);
        }
    }
#pragma unroll
    for (int nt = 0; nt < 4; ++nt) {
        int col = nbase + nt * 16 + l15;
        float bv = (float)bias[col];
#pragma unroll
        for (int r = 0; r < 4; ++r) {
            int row = mbase + m0 + quad * 4 + r;
            float v = acc[nt][r] + bv;
            if (mode == 0) {
                int t = col >> 9, hh = (col >> 6) & 7, d = col & 63;
                if (t == 0) v *= CMUL;
                ((bf16*)outv)[((size_t)t * H + hh) * S * D + (size_t)row * D + d] = (bf16)v;
            } else {
                ((float*)outv)[(size_t)row * E + col] = v;
            }
        }
    }
}

// ---------------------------------------------------------------------------
// Fused flash attention. 256-thread blocks (4 waves), Q-tile 64, K-tile 64.
// K fragments, V tile, and mask words all prefetched ONE FULL ITERATION ahead
// in registers (A/B ping-pong, explicit 2-step loop). K never touches LDS.
// V transposed via double-buffered LDS; one barrier per iteration.
// Ps aliases Qs. exp2-domain fixed softmax, K-split. grid: (S/64, H, nsplit).
// ---------------------------------------------------------------------------
__global__ __launch_bounds__(256) void attn(const bf16* __restrict__ Qp,
                                            const bf16* __restrict__ Kp,
                                            const bf16* __restrict__ Vp,
                                            const unsigned long long* __restrict__ bitsT,
                                            float* __restrict__ Opart,
                                            float* __restrict__ Lpart,
                                            int ktper)
{
    __shared__ __align__(16) char smem[25600];
    bf16 (*Qs)[72]      = (bf16(*)[72])smem;                // 64x72 (9216 B)
    bf16 (*Ps)[16][64]  = (bf16(*)[16][64])smem;            // aliases Qs after use
    bf16 (*Vts)[64][64] = (bf16(*)[64][64])(smem + 9216);   // 2 x 64x64 swizzled V^T

    const int tid  = threadIdx.x;
    const int wid  = tid >> 6, lane = tid & 63;
    const int quad = lane >> 4, l15 = lane & 15;
    const int qt = blockIdx.x, h = blockIdx.y, split = blockIdx.z;
    const int qbase = qt * 64;
    const int m0 = wid * 16;
    const bf16* Qh = Qp + (size_t)h * S * D;
    const bf16* Kh = Kp + (size_t)h * S * D;
    const bf16* Vh = Vp + (size_t)h * S * D;

    const int vt0 = (tid & 31) * 2, vd0 = (tid >> 5) * 8;

    // stage Q once
#pragma unroll
    for (int i = 0; i < 2; ++i) {
        int slot = tid + i * 256;
        int row = slot >> 3, kg = slot & 7;
        *(uint4*)&Qs[row][kg * 8] = *(const uint4*)&Qh[(size_t)(qbase + row) * D + kg * 8];
    }
    __syncthreads();
    bf16x8 aq0 = *(bf16x8*)&Qs[m0 + l15][quad * 8];
    bf16x8 aq1 = *(bf16x8*)&Qs[m0 + l15][32 + quad * 8];

    // ones B-fragment for l-sum MFMA (col 0 only)
    bf16x8 bl;
    {
        union { short s; bf16 b; } one; one.b = (bf16)1.0f;
        short v = (l15 == 0) ? one.s : (short)0;
#pragma unroll
        for (int j = 0; j < 8; ++j) bl[j] = v;
    }

    f32x4 o[4];
#pragma unroll
    for (int dt = 0; dt < 4; ++dt) o[dt] = (f32x4){0.f, 0.f, 0.f, 0.f};
    f32x4 accl = (f32x4){0.f, 0.f, 0.f, 0.f};

    const int kt0 = split * ktper, kt1 = kt0 + ktper;

    // advancing per-lane base pointers
    const bf16* kp = Kh + (size_t)kt0 * 64 * D + l15 * D + quad * 8;
    const bf16* vp = Vh + (size_t)kt0 * 64 * D + (size_t)vt0 * D + vd0;
    const unsigned long long* mb = bitsT + (size_t)kt0 * S + qbase + m0 + quad * 4;

    const int ksw_rd = (l15 & 7);               // Vts read swizzle key
    const int pkey   = ((l15 >> 1) & 7);        // Ps read swizzle key

    // prefetch set A for kt0
    u4bf8 kfA[8], kfB[8];
    uint4 vqA0, vqA1, vqB0, vqB1;
    uint4 mwA[2], mwB[2];
#pragma unroll
    for (int nt = 0; nt < 4; ++nt) {
        kfA[nt * 2 + 0].u = *(const uint4*)(kp + nt * 16 * D);
        kfA[nt * 2 + 1].u = *(const uint4*)(kp + nt * 16 * D + 32);
    }
    vqA0 = *(const uint4*)vp;
    vqA1 = *(const uint4*)(vp + D);
    mwA[0] = *(const uint4*)mb;
    mwA[1] = *(const uint4*)(mb + 2);
    kp += 64 * D; vp += 64 * D; mb += S;

    auto step = [&](int kt, u4bf8* kf, uint4& v0, uint4& v1, uint4* mw,
                    u4bf8* nkf, uint4& nv0, uint4& nv1, uint4* nmw) {
        const int buf = kt & 1;
        // issue next-iteration loads (drain across this whole iteration)
        if (kt + 1 < kt1) {
#pragma unroll
            for (int nt = 0; nt < 4; ++nt) {
                nkf[nt * 2 + 0].u = *(const uint4*)(kp + nt * 16 * D);
                nkf[nt * 2 + 1].u = *(const uint4*)(kp + nt * 16 * D + 32);
            }
            nv0 = *(const uint4*)vp;
            nv1 = *(const uint4*)(vp + D);
            nmw[0] = *(const uint4*)mb;
            nmw[1] = *(const uint4*)(mb + 2);
            kp += 64 * D; vp += 64 * D; mb += S;
        }
        // V regs (this tile) -> LDS buf, v_perm packed pair stores
        {
            const unsigned int* w0 = (const unsigned int*)&v0;
            const unsigned int* w1 = (const unsigned int*)&v1;
#pragma unroll
            for (int j = 0; j < 8; ++j) {
                unsigned int pk = __builtin_amdgcn_perm(
                    w1[j >> 1], w0[j >> 1],
                    (j & 1) ? 0x07060302u : 0x05040100u);
                *(unsigned int*)&Vts[buf][vd0 + j][vt0 ^ (j * 8)] = pk;
            }
        }
        __syncthreads();   // V tile visible; K frags already resident in regs

        // S = (Q*CMUL) K^T  (exp2 domain)
        f32x4 sc[4];
        {
            f32x4 z = (f32x4){0.f, 0.f, 0.f, 0.f};
#pragma unroll
            for (int nt = 0; nt < 4; ++nt) {
                sc[nt] = __builtin_amdgcn_mfma_f32_16x16x32_bf16(aq0, kf[nt * 2 + 0].b, z, 0, 0, 0);
                sc[nt] = __builtin_amdgcn_mfma_f32_16x16x32_bf16(aq1, kf[nt * 2 + 1].b, sc[nt], 0, 0, 0);
            }
        }
        // p = exp2(s), masked -> 0; write swizzled P tile (wave-private)
        const unsigned long long* mwq = (const unsigned long long*)mw;
#pragma unroll
        for (int r = 0; r < 4; ++r) {
            unsigned long long sh = mwq[r] >> l15;
            int row = quad * 4 + r;
            int key = ((row >> 1) & 7) << 3;
#pragma unroll
            for (int nt = 0; nt < 4; ++nt) {
                float p = __builtin_amdgcn_exp2f(sc[nt][r]);
                bool ok = (sh >> (nt * 16)) & 1ull;
                p = ok ? p : 0.f;
                Ps[wid][row][(nt * 16 + l15) ^ key] = (bf16)p;
            }
        }
        // O += P V ; l += P 1
        bf16x8 ap0 = *(bf16x8*)&Ps[wid][l15][(quad ^ pkey) * 8];
        bf16x8 ap1 = *(bf16x8*)&Ps[wid][l15][((quad + 4) ^ pkey) * 8];
        accl = __builtin_amdgcn_mfma_f32_16x16x32_bf16(ap0, bl, accl, 0, 0, 0);
        accl = __builtin_amdgcn_mfma_f32_16x16x32_bf16(ap1, bl, accl, 0, 0, 0);
#pragma unroll
        for (int dt = 0; dt < 4; ++dt) {
            bf16x8 bv0 = *(bf16x8*)&Vts[buf][dt * 16 + l15][(quad ^ ksw_rd) * 8];
            bf16x8 bv1 = *(bf16x8*)&Vts[buf][dt * 16 + l15][((quad + 4) ^ ksw_rd) * 8];
            o[dt] = __builtin_amdgcn_mfma_f32_16x16x32_bf16(ap0, bv0, o[dt], 0, 0, 0);
            o[dt] = __builtin_amdgcn_mfma_f32_16x16x32_bf16(ap1, bv1, o[dt], 0, 0, 0);
        }
    };

    for (int kt = kt0; kt < kt1; kt += 2) {
        step(kt,     kfA, vqA0, vqA1, mwA, kfB, vqB0, vqB1, mwB);
        step(kt + 1, kfB, vqB0, vqB1, mwB, kfA, vqA0, vqA1, mwA);
    }

    // epilogue: store fp32 partials; l lives in lanes l15==0 (col 0 of accl)
    float* Op = Opart + (size_t)(split * H + h) * S * D;
    float* Lp = Lpart + (size_t)(split * H + h) * S;
#pragma unroll
    for (int r = 0; r < 4; ++r) {
        int row = qbase + m0 + quad * 4 + r;
        if (l15 == 0) Lp[row] = accl[r];
#pragma unroll
        for (int dt = 0; dt < 4; ++dt)
            Op[(size_t)row * D + dt * 16 + l15] = o[dt][r];
    }
}

// ---------------------------------------------------------------------------
// Combine K-split partials: Ow[s][h*64+d] = sum_s Opart / sum_s Lpart (bf16).
// ---------------------------------------------------------------------------
__global__ __launch_bounds__(256) void combine(const float* __restrict__ Opart,
                                               const float* __restrict__ Lpart,
                                               bf16* __restrict__ Ow, int nsplit)
{
    int g = blockIdx.x * 256 + threadIdx.x;
    int e = g * 4;
    int row = e >> 9;
    int c = e & 511;
    int h = c >> 6, d = c & 63;
    size_t base = ((size_t)h * S + row) * D + d;
    const size_t oh = (size_t)H * S * D;
    float ax = 0.f, ay = 0.f, az = 0.f, aw = 0.f, l = 0.f;
    for (int s = 0; s < nsplit; ++s) {
        float4 a = *(const float4*)(Opart + (size_t)s * oh + base);
        ax += a.x; ay += a.y; az += a.z; aw += a.w;
        l += Lpart[(size_t)s * H * S + (size_t)h * S + row];
    }
    float inv = (l > 0.f) ? 1.f / l : 0.f;
    union { bf16 x[4]; uint2 u; } ov;
    ov.x[0] = (bf16)(ax * inv);
    ov.x[1] = (bf16)(ay * inv);
    ov.x[2] = (bf16)(az * inv);
    ov.x[3] = (bf16)(aw * inv);
    *(uint2*)(Ow + (size_t)row * E + c) = ov.u;
}

// ---------------------------------------------------------------------------
extern "C" void kernel_launch(void* const* d_in, const int* in_sizes, int n_in,
                              void* d_out, int out_size, void* d_ws, size_t ws_size,
                              hipStream_t stream)
{
    char* ws = (char*)d_ws;
    const size_t MB = (size_t)1 << 20;
    bf16* Qw   = (bf16*)(ws + 0 * MB);        // 12 MB: Q|K|V planar cat
    bf16* Kw   = (bf16*)(ws + 4 * MB);
    bf16* Vw   = (bf16*)(ws + 8 * MB);
    bf16* Ow   = (bf16*)(ws + 12 * MB);       // 4 MB [s][512] bf16
    unsigned long long* bitsT = (unsigned long long*)(ws + 16 * MB); // 2 MB
    bf16* xb   = (bf16*)(ws + 18 * MB);       // 4 MB
    bf16* Wcat = (bf16*)(ws + 22 * MB);       // 1.5 MB
    bf16* Wob  = (bf16*)(ws + 24 * MB);       // 0.5 MB
    bf16* bcat = (bf16*)(ws + 25 * MB);
    bf16* bob  = (bf16*)(ws + 25 * MB + 8192);
    int*  flag = (int*)(ws + 25 * MB + 16384);
    float* Opart = (float*)(ws + 26 * MB);    // nsplit x 8 MB

    int nsplit = (ws_size >= 59 * MB) ? 4 : 2;
    int ktper  = (S / 64) / nsplit;
    float* Lpart = (float*)(ws + 26 * MB + (size_t)nsplit * 8 * MB);

    hipLaunchKernelGGL(sniff, dim3(1), dim3(64), 0, stream,
                       (const unsigned int*)d_in[9], flag);
    hipLaunchKernelGGL(convert_all, dim3(1024), dim3(256), 0, stream,
                       (const float*)d_in[0], (const float*)d_in[1],
                       (const float*)d_in[3], (const float*)d_in[5],
                       (const float*)d_in[7], (const float*)d_in[2],
                       (const float*)d_in[4], (const float*)d_in[6],
                       (const float*)d_in[8],
                       xb, Wcat, Wob, bcat, bob);
    hipLaunchKernelGGL(pack_mask, dim3(1024), dim3(256), 0, stream, d_in[9], bitsT, flag);
    hipLaunchKernelGGL(gemm64, dim3(24, 64), dim3(256), 0, stream, xb, Wcat, bcat, (void*)Qw, 0);
    hipLaunchKernelGGL(attn, dim3(S / 64, H, nsplit), dim3(256), 0, stream,
                       Qw, Kw, Vw, bitsT, Opart, Lpart, ktper);
    hipLaunchKernelGGL(combine, dim3(2048), dim3(256), 0, stream, Opart, Lpart, Ow, nsplit);
    hipLaunchKernelGGL(gemm64, dim3(8, 64), dim3(256), 0, stream, Ow, Wob, bob, d_out, 1);
}

// Round 11
// 334.302 us; speedup vs baseline: 1.2353x; 1.2261x over previous
//
#include <hip/hip_runtime.h>
#include <hip/hip_bf16.h>
#include <stdint.h>

#define S 4096
#define E 512
#define H 8
#define D 64
#define MROW 5000        // mask row stride (MAX_GENES)

typedef __hip_bfloat16 bf16;
typedef __attribute__((ext_vector_type(8))) short bf16x8;
typedef __attribute__((ext_vector_type(4))) float f32x4;

#define CMUL (0.125f * 1.4426950408889634f)  // scale * log2(e), folded into Q

// ---------------------------------------------------------------------------
// prep: fused mask-pack (blocks 0..1023) + fp32->bf16 convert (1024..2047).
// Mask dtype decided per-wave from first 512 words (byte-bool pattern:
// word>1 with all bytes<=1). bitsT layout TRANSPOSED: bitsT[word][row].
// ---------------------------------------------------------------------------
__global__ __launch_bounds__(256) void prep(
    const void* __restrict__ mask, unsigned long long* __restrict__ bitsT,
    const float* __restrict__ x,  const float* __restrict__ wq,
    const float* __restrict__ wk, const float* __restrict__ wv,
    const float* __restrict__ wo, const float* __restrict__ bq,
    const float* __restrict__ bk, const float* __restrict__ bv,
    const float* __restrict__ bo,
    bf16* __restrict__ xb, bf16* __restrict__ wcat, bf16* __restrict__ wob,
    bf16* __restrict__ bcat, bf16* __restrict__ bob)
{
    const int b = blockIdx.x;
    const int tid = threadIdx.x;
    if (b < 1024) {
        // --- local flag: every wave scans words 0..511 identically ---
        const unsigned int* mw32 = (const unsigned int*)mask;
        int lane = tid & 63;
        int hit = 0;
#pragma unroll
        for (int i = 0; i < 8; ++i) {
            unsigned int w = mw32[lane + i * 64];
            if (w > 1u && (w & 0xFEFEFEFEu) == 0u) hit = 1;
        }
        const bool isbyte = (__ballot(hit) != 0ull);
        // --- pack ---
        int wid  = (b * 256 + tid) >> 6;
        int nwav = (1024 * 256) >> 6;
        int total = (S / 64) * S;
        for (int w = wid; w < total; w += nwav) {
            int word = w >> 12;          // 0..63
            int row  = w & (S - 1);      // 0..4095
            int col  = word * 64 + lane;
            unsigned int v;
            if (isbyte) v = ((const unsigned char*)mask)[(size_t)row * MROW + col];
            else        v = ((const unsigned int*)mask)[(size_t)row * MROW + col];
            unsigned long long bb = __ballot(v != 0u);
            if (lane == 0) bitsT[(size_t)word * S + row] = bb;
        }
    } else {
        // --- convert ---
        const float* srcs[9] = {x, wq, wk, wv, wo, bq, bk, bv, bo};
        bf16* dsts[9] = {xb, wcat, wcat + 262144, wcat + 524288, wob,
                         bcat, bcat + 512, bcat + 1024, bob};
        const int cnts[9] = {2097152, 262144, 262144, 262144, 262144,
                             512, 512, 512, 512};
        const int ngroups = (2097152 + 4 * 262144 + 4 * 512) / 4;
        for (int g = (b - 1024) * 256 + tid; g < ngroups; g += 1024 * 256) {
            int e = g * 4;
            int seg = 0;
            while (e >= cnts[seg]) { e -= cnts[seg]; ++seg; }
            float4 v = *(const float4*)(srcs[seg] + e);
            union { bf16 h[4]; uint2 u; } cv;
            cv.h[0] = (bf16)v.x; cv.h[1] = (bf16)v.y;
            cv.h[2] = (bf16)v.z; cv.h[3] = (bf16)v.w;
            *(uint2*)(dsts[seg] + e) = cv.u;
        }
    }
}

// ---------------------------------------------------------------------------
// QKV GEMM: C(64x64 tile) = A(Mx512) @ W^T + bias, N=1536 fused.
// out planar Q|K|V, each [h][s][64] bf16; Q pre-scaled by CMUL.
// ---------------------------------------------------------------------------
__global__ __launch_bounds__(256) void gemm_qkv(const bf16* __restrict__ A,
                                                const bf16* __restrict__ W,
                                                const bf16* __restrict__ bias,
                                                bf16* __restrict__ out)
{
    __shared__ bf16 As[64][72];
    __shared__ bf16 Bs[64][72];
    const int tid  = threadIdx.x;
    const int wid  = tid >> 6, lane = tid & 63;
    const int quad = lane >> 4, l15 = lane & 15;
    const int nbase = blockIdx.x * 64;
    const int mbase = blockIdx.y * 64;
    const int m0 = wid * 16;

    f32x4 acc[4];
#pragma unroll
    for (int i = 0; i < 4; ++i) acc[i] = (f32x4){0.f, 0.f, 0.f, 0.f};

    for (int kt = 0; kt < E / 64; ++kt) {
        const int kb = kt * 64;
        __syncthreads();
#pragma unroll
        for (int i = 0; i < 2; ++i) {
            int slot = tid + i * 256;
            int row = slot >> 3, kg = slot & 7;
            *(uint4*)&As[row][kg * 8] = *(const uint4*)&A[(size_t)(mbase + row) * E + kb + kg * 8];
            *(uint4*)&Bs[row][kg * 8] = *(const uint4*)&W[(size_t)(nbase + row) * E + kb + kg * 8];
        }
        __syncthreads();
        bf16x8 a0 = *(bf16x8*)&As[m0 + l15][quad * 8];
        bf16x8 a1 = *(bf16x8*)&As[m0 + l15][32 + quad * 8];
#pragma unroll
        for (int nt = 0; nt < 4; ++nt) {
            bf16x8 b0 = *(bf16x8*)&Bs[nt * 16 + l15][quad * 8];
            bf16x8 b1 = *(bf16x8*)&Bs[nt * 16 + l15][32 + quad * 8];
            acc[nt] = __builtin_amdgcn_mfma_f32_16x16x32_bf16(a0, b0, acc[nt], 0, 0, 0);
            acc[nt] = __builtin_amdgcn_mfma_f32_16x16x32_bf16(a1, b1, acc[nt], 0, 0, 0);
        }
    }
#pragma unroll
    for (int nt = 0; nt < 4; ++nt) {
        int col = nbase + nt * 16 + l15;
        float bv = (float)bias[col];
#pragma unroll
        for (int r = 0; r < 4; ++r) {
            int row = mbase + m0 + quad * 4 + r;
            float v = acc[nt][r] + bv;
            int t = col >> 9, hh = (col >> 6) & 7, d = col & 63;
            if (t == 0) v *= CMUL;
            out[((size_t)t * H + hh) * S * D + (size_t)row * D + d] = (bf16)v;
        }
    }
}

// ---------------------------------------------------------------------------
// Fused flash attention (R8 structure: K/V via LDS, swizzled, 2 barriers,
// register prefetch). Mask via transposed bitsT -> 2 dwordx4 per iter.
// grid: (S/64, H, nsplit), block 256 (4 waves x 16 q-rows).
// ---------------------------------------------------------------------------
__global__ __launch_bounds__(256) void attn(const bf16* __restrict__ Qp,
                                            const bf16* __restrict__ Kp,
                                            const bf16* __restrict__ Vp,
                                            const unsigned long long* __restrict__ bitsT,
                                            float* __restrict__ Opart,
                                            float* __restrict__ Lpart,
                                            int ktper)
{
    __shared__ __align__(16) char smem[25600];
    bf16 (*Qs)[72]     = (bf16(*)[72])smem;                 // 64x72 (9216 B)
    bf16 (*Ps)[16][64] = (bf16(*)[16][64])smem;             // aliases Qs after use
    bf16 (*Ks)[64]     = (bf16(*)[64])(smem + 9216);        // 64x64 swizzled
    bf16 (*Vts)[64]    = (bf16(*)[64])(smem + 17408);       // 64x64 swizzled V^T

    const int tid  = threadIdx.x;
    const int wid  = tid >> 6, lane = tid & 63;
    const int quad = lane >> 4, l15 = lane & 15;
    const int qt = blockIdx.x, h = blockIdx.y, split = blockIdx.z;
    const int qbase = qt * 64;
    const int m0 = wid * 16;
    const bf16* Qh = Qp + (size_t)h * S * D;
    const bf16* Kh = Kp + (size_t)h * S * D;
    const bf16* Vh = Vp + (size_t)h * S * D;

    const int krow0 = tid >> 3, kkg = tid & 7;
    const int krow1 = (tid + 256) >> 3;
    const int ksw0 = (kkg ^ (krow0 & 7)) * 8;
    const int ksw1 = (kkg ^ (krow1 & 7)) * 8;
    const int vt0 = (tid & 31) * 2, vd0 = (tid >> 5) * 8;

#pragma unroll
    for (int i = 0; i < 2; ++i) {
        int slot = tid + i * 256;
        int row = slot >> 3, kg = slot & 7;
        *(uint4*)&Qs[row][kg * 8] = *(const uint4*)&Qh[(size_t)(qbase + row) * D + kg * 8];
    }
    __syncthreads();
    bf16x8 aq0 = *(bf16x8*)&Qs[m0 + l15][quad * 8];
    bf16x8 aq1 = *(bf16x8*)&Qs[m0 + l15][32 + quad * 8];

    bf16x8 bl;
    {
        union { short s; bf16 b; } one; one.b = (bf16)1.0f;
        short v = (l15 == 0) ? one.s : (short)0;
#pragma unroll
        for (int j = 0; j < 8; ++j) bl[j] = v;
    }

    f32x4 o[4];
#pragma unroll
    for (int dt = 0; dt < 4; ++dt) o[dt] = (f32x4){0.f, 0.f, 0.f, 0.f};
    f32x4 accl = (f32x4){0.f, 0.f, 0.f, 0.f};

    const int kt0 = split * ktper, kt1 = kt0 + ktper;

    uint4 kq0, kq1, vq0, vq1;
    {
        const int kbase = kt0 * 64;
        kq0 = *(const uint4*)&Kh[(size_t)(kbase + krow0) * D + kkg * 8];
        kq1 = *(const uint4*)&Kh[(size_t)(kbase + krow1) * D + kkg * 8];
        vq0 = *(const uint4*)&Vh[(size_t)(kbase + vt0) * D + vd0];
        vq1 = *(const uint4*)&Vh[(size_t)(kbase + vt0 + 1) * D + vd0];
    }

    // transposed mask pointer: rows quad*4..+3 at column-block kt
    const unsigned long long* mb = bitsT + (size_t)kt0 * S + qbase + m0 + quad * 4;

    const int ksw_rd = (l15 & 7);               // K/V read swizzle key
    const int pkey   = ((l15 >> 1) & 7);        // Ps read swizzle key
    for (int kt = kt0; kt < kt1; ++kt) {
        __syncthreads();   // previous tile consumed (guards Qs->Ps alias too)
        *(uint4*)&Ks[krow0][ksw0] = kq0;
        *(uint4*)&Ks[krow1][ksw1] = kq1;
        {
            const unsigned short* p0 = (const unsigned short*)&vq0;
            const unsigned short* p1 = (const unsigned short*)&vq1;
#pragma unroll
            for (int j = 0; j < 8; ++j) {
                unsigned int pk = (unsigned int)p0[j] | ((unsigned int)p1[j] << 16);
                *(unsigned int*)&Vts[vd0 + j][vt0 ^ (j * 8)] = pk;
            }
        }
        if (kt + 1 < kt1) {
            const int kb2 = (kt + 1) * 64;
            kq0 = *(const uint4*)&Kh[(size_t)(kb2 + krow0) * D + kkg * 8];
            kq1 = *(const uint4*)&Kh[(size_t)(kb2 + krow1) * D + kkg * 8];
            vq0 = *(const uint4*)&Vh[(size_t)(kb2 + vt0) * D + vd0];
            vq1 = *(const uint4*)&Vh[(size_t)(kb2 + vt0 + 1) * D + vd0];
        }
        uint4 mv0 = *(const uint4*)mb;
        uint4 mv1 = *(const uint4*)(mb + 2);
        mb += S;
        __syncthreads();   // K/V tile visible

        f32x4 sc[4];
        {
            f32x4 z = (f32x4){0.f, 0.f, 0.f, 0.f};
#pragma unroll
            for (int nt = 0; nt < 4; ++nt) {
                bf16x8 b0 = *(bf16x8*)&Ks[nt * 16 + l15][(quad ^ ksw_rd) * 8];
                bf16x8 b1 = *(bf16x8*)&Ks[nt * 16 + l15][((quad + 4) ^ ksw_rd) * 8];
                sc[nt] = __builtin_amdgcn_mfma_f32_16x16x32_bf16(aq0, b0, z, 0, 0, 0);
                sc[nt] = __builtin_amdgcn_mfma_f32_16x16x32_bf16(aq1, b1, sc[nt], 0, 0, 0);
            }
        }
        unsigned long long mwq[4];
        mwq[0] = ((unsigned long long)mv0.y << 32) | mv0.x;
        mwq[1] = ((unsigned long long)mv0.w << 32) | mv0.z;
        mwq[2] = ((unsigned long long)mv1.y << 32) | mv1.x;
        mwq[3] = ((unsigned long long)mv1.w << 32) | mv1.z;
#pragma unroll
        for (int r = 0; r < 4; ++r) {
            unsigned long long sh = mwq[r] >> l15;
            int row = quad * 4 + r;
            int key = ((row >> 1) & 7) << 3;
#pragma unroll
            for (int nt = 0; nt < 4; ++nt) {
                float p = __builtin_amdgcn_exp2f(sc[nt][r]);
                bool ok = (sh >> (nt * 16)) & 1ull;
                p = ok ? p : 0.f;
                Ps[wid][row][(nt * 16 + l15) ^ key] = (bf16)p;
            }
        }
        bf16x8 ap0 = *(bf16x8*)&Ps[wid][l15][(quad ^ pkey) * 8];
        bf16x8 ap1 = *(bf16x8*)&Ps[wid][l15][((quad + 4) ^ pkey) * 8];
        accl = __builtin_amdgcn_mfma_f32_16x16x32_bf16(ap0, bl, accl, 0, 0, 0);
        accl = __builtin_amdgcn_mfma_f32_16x16x32_bf16(ap1, bl, accl, 0, 0, 0);
#pragma unroll
        for (int dt = 0; dt < 4; ++dt) {
            bf16x8 bv0 = *(bf16x8*)&Vts[dt * 16 + l15][(quad ^ ksw_rd) * 8];
            bf16x8 bv1 = *(bf16x8*)&Vts[dt * 16 + l15][((quad + 4) ^ ksw_rd) * 8];
            o[dt] = __builtin_amdgcn_mfma_f32_16x16x32_bf16(ap0, bv0, o[dt], 0, 0, 0);
            o[dt] = __builtin_amdgcn_mfma_f32_16x16x32_bf16(ap1, bv1, o[dt], 0, 0, 0);
        }
    }
    float* Op = Opart + (size_t)(split * H + h) * S * D;
    float* Lp = Lpart + (size_t)(split * H + h) * S;
#pragma unroll
    for (int r = 0; r < 4; ++r) {
        int row = qbase + m0 + quad * 4 + r;
        if (l15 == 0) Lp[row] = accl[r];
#pragma unroll
        for (int dt = 0; dt < 4; ++dt)
            Op[(size_t)row * D + dt * 16 + l15] = o[dt][r];
    }
}

// ---------------------------------------------------------------------------
// Output GEMM with fused K-split combine: A[row][c] = (sum_s Opart)/(sum_s L)
// normalized to bf16 during LDS staging (head = K-tile index since c=kt*64+d).
// out = A @ Wo^T + bo, fp32 into d_out. grid (8, 64), block 256.
// ---------------------------------------------------------------------------
__global__ __launch_bounds__(256) void gemm_out(const float* __restrict__ Opart,
                                                const float* __restrict__ Lpart,
                                                const bf16* __restrict__ W,
                                                const bf16* __restrict__ bias,
                                                float* __restrict__ out, int nsplit)
{
    __shared__ bf16 As[64][72];
    __shared__ bf16 Bs[64][72];
    const int tid  = threadIdx.x;
    const int wid  = tid >> 6, lane = tid & 63;
    const int quad = lane >> 4, l15 = lane & 15;
    const int nbase = blockIdx.x * 64;
    const int mbase = blockIdx.y * 64;
    const int m0 = wid * 16;
    const size_t oh = (size_t)H * S * D;

    f32x4 acc[4];
#pragma unroll
    for (int i = 0; i < 4; ++i) acc[i] = (f32x4){0.f, 0.f, 0.f, 0.f};

    for (int kt = 0; kt < E / 64; ++kt) {
        const int kb = kt * 64;
        const int h = kt;                    // head index for this K-tile
        __syncthreads();
#pragma unroll
        for (int i = 0; i < 2; ++i) {
            int slot = tid + i * 256;
            int row = slot >> 3, kg = slot & 7;
            int qrow = mbase + row;
            size_t base = ((size_t)h * S + qrow) * D + kg * 8;
            float a[8] = {0, 0, 0, 0, 0, 0, 0, 0};
            float l = 0.f;
            for (int s = 0; s < nsplit; ++s) {
                float4 p0 = *(const float4*)(Opart + (size_t)s * oh + base);
                float4 p1 = *(const float4*)(Opart + (size_t)s * oh + base + 4);
                a[0] += p0.x; a[1] += p0.y; a[2] += p0.z; a[3] += p0.w;
                a[4] += p1.x; a[5] += p1.y; a[6] += p1.z; a[7] += p1.w;
                l += Lpart[(size_t)s * H * S + (size_t)h * S + qrow];
            }
            float inv = (l > 0.f) ? 1.f / l : 0.f;
            union { bf16 hh[8]; uint4 u; } cv;
#pragma unroll
            for (int j = 0; j < 8; ++j) cv.hh[j] = (bf16)(a[j] * inv);
            *(uint4*)&As[row][kg * 8] = cv.u;
            *(uint4*)&Bs[row][kg * 8] = *(const uint4*)&W[(size_t)(nbase + row) * E + kb + kg * 8];
        }
        __syncthreads();
        bf16x8 a0 = *(bf16x8*)&As[m0 + l15][quad * 8];
        bf16x8 a1 = *(bf16x8*)&As[m0 + l15][32 + quad * 8];
#pragma unroll
        for (int nt = 0; nt < 4; ++nt) {
            bf16x8 b0 = *(bf16x8*)&Bs[nt * 16 + l15][quad * 8];
            bf16x8 b1 = *(bf16x8*)&Bs[nt * 16 + l15][32 + quad * 8];
            acc[nt] = __builtin_amdgcn_mfma_f32_16x16x32_bf16(a0, b0, acc[nt], 0, 0, 0);
            acc[nt] = __builtin_amdgcn_mfma_f32_16x16x32_bf16(a1, b1, acc[nt], 0, 0, 0);
        }
    }
#pragma unroll
    for (int nt = 0; nt < 4; ++nt) {
        int col = nbase + nt * 16 + l15;
        float bv = (float)bias[col];
#pragma unroll
        for (int r = 0; r < 4; ++r) {
            int row = mbase + m0 + quad * 4 + r;
            out[(size_t)row * E + col] = acc[nt][r] + bv;
        }
    }
}

// ---------------------------------------------------------------------------
extern "C" void kernel_launch(void* const* d_in, const int* in_sizes, int n_in,
                              void* d_out, int out_size, void* d_ws, size_t ws_size,
                              hipStream_t stream)
{
    char* ws = (char*)d_ws;
    const size_t MB = (size_t)1 << 20;
    bf16* Qw   = (bf16*)(ws + 0 * MB);        // 12 MB: Q|K|V planar cat
    bf16* Kw   = (bf16*)(ws + 4 * MB);
    bf16* Vw   = (bf16*)(ws + 8 * MB);
    unsigned long long* bitsT = (unsigned long long*)(ws + 16 * MB); // 2 MB
    bf16* xb   = (bf16*)(ws + 18 * MB);       // 4 MB
    bf16* Wcat = (bf16*)(ws + 22 * MB);       // 1.5 MB
    bf16* Wob  = (bf16*)(ws + 24 * MB);       // 0.5 MB
    bf16* bcat = (bf16*)(ws + 25 * MB);
    bf16* bob  = (bf16*)(ws + 25 * MB + 8192);
    float* Opart = (float*)(ws + 26 * MB);    // nsplit x 8 MB

    int nsplit = (ws_size >= 59 * MB) ? 4 : 2;
    int ktper  = (S / 64) / nsplit;
    float* Lpart = (float*)(ws + 26 * MB + (size_t)nsplit * 8 * MB);

    hipLaunchKernelGGL(prep, dim3(2048), dim3(256), 0, stream,
                       d_in[9], bitsT,
                       (const float*)d_in[0], (const float*)d_in[1],
                       (const float*)d_in[3], (const float*)d_in[5],
                       (const float*)d_in[7], (const float*)d_in[2],
                       (const float*)d_in[4], (const float*)d_in[6],
                       (const float*)d_in[8],
                       xb, Wcat, Wob, bcat, bob);
    hipLaunchKernelGGL(gemm_qkv, dim3(24, 64), dim3(256), 0, stream,
                       xb, Wcat, bcat, Qw);
    hipLaunchKernelGGL(attn, dim3(S / 64, H, nsplit), dim3(256), 0, stream,
                       Qw, Kw, Vw, bitsT, Opart, Lpart, ktper);
    hipLaunchKernelGGL(gemm_out, dim3(8, 64), dim3(256), 0, stream,
                       Opart, Lpart, Wob, bob, (float*)d_out, nsplit);
}

// Round 12
// 312.668 us; speedup vs baseline: 1.3208x; 1.0692x over previous
//
#include <hip/hip_runtime.h>
#include <hip/hip_bf16.h>
#include <stdint.h>

#define S 4096
#define E 512
#define H 8
#define D 64
#define MROW 5000        // mask row stride (MAX_GENES)

typedef __hip_bfloat16 bf16;
typedef __attribute__((ext_vector_type(8))) short bf16x8;
typedef __attribute__((ext_vector_type(4))) float f32x4;

#define CMUL (0.125f * 1.4426950408889634f)  // scale * log2(e), folded into Q

// ---------------------------------------------------------------------------
// prep: all 2048 blocks convert fp32->bf16 (12 MB), then pack mask (100 MB).
// Balanced so the mask read gets full device bandwidth.
// bits layout: bits[row][word] (row-major, 8B words).
// ---------------------------------------------------------------------------
__global__ __launch_bounds__(256) void prep(
    const void* __restrict__ mask, unsigned long long* __restrict__ bits,
    const float* __restrict__ x,  const float* __restrict__ wq,
    const float* __restrict__ wk, const float* __restrict__ wv,
    const float* __restrict__ wo, const float* __restrict__ bq,
    const float* __restrict__ bk, const float* __restrict__ bv,
    const float* __restrict__ bo,
    bf16* __restrict__ xb, bf16* __restrict__ wcat, bf16* __restrict__ wob,
    bf16* __restrict__ bcat, bf16* __restrict__ bob)
{
    const int tid = threadIdx.x;
    const int b   = blockIdx.x;
    // --- convert (grid-stride over all blocks) ---
    {
        const float* srcs[9] = {x, wq, wk, wv, wo, bq, bk, bv, bo};
        bf16* dsts[9] = {xb, wcat, wcat + 262144, wcat + 524288, wob,
                         bcat, bcat + 512, bcat + 1024, bob};
        const int cnts[9] = {2097152, 262144, 262144, 262144, 262144,
                             512, 512, 512, 512};
        const int ngroups = (2097152 + 4 * 262144 + 4 * 512) / 4;
        for (int g = b * 256 + tid; g < ngroups; g += 2048 * 256) {
            int e = g * 4;
            int seg = 0;
            while (e >= cnts[seg]) { e -= cnts[seg]; ++seg; }
            float4 v = *(const float4*)(srcs[seg] + e);
            union { bf16 h[4]; uint2 u; } cv;
            cv.h[0] = (bf16)v.x; cv.h[1] = (bf16)v.y;
            cv.h[2] = (bf16)v.z; cv.h[3] = (bf16)v.w;
            *(uint2*)(dsts[seg] + e) = cv.u;
        }
    }
    // --- pack mask; per-wave dtype flag from first 512 words ---
    {
        const unsigned int* mw32 = (const unsigned int*)mask;
        int lane = tid & 63;
        int hit = 0;
#pragma unroll
        for (int i = 0; i < 8; ++i) {
            unsigned int w = mw32[lane + i * 64];
            if (w > 1u && (w & 0xFEFEFEFEu) == 0u) hit = 1;
        }
        const bool isbyte = (__ballot(hit) != 0ull);
        int wid  = (b * 256 + tid) >> 6;
        int nwav = (2048 * 256) >> 6;
        int total = S * (S / 64);
        for (int w = wid; w < total; w += nwav) {
            int row  = w >> 6;
            int word = w & 63;
            int col  = word * 64 + lane;
            unsigned int v;
            if (isbyte) v = ((const unsigned char*)mask)[(size_t)row * MROW + col];
            else        v = ((const unsigned int*)mask)[(size_t)row * MROW + col];
            unsigned long long bb = __ballot(v != 0u);
            if (lane == 0) bits[(size_t)row * 64 + word] = bb;
        }
    }
}

// ---------------------------------------------------------------------------
// QKV GEMM: C(64x64 tile) = A(Mx512) @ W^T + bias, N=1536 fused.
// out planar Q|K|V, each [h][s][64] bf16; Q pre-scaled by CMUL.
// ---------------------------------------------------------------------------
__global__ __launch_bounds__(256) void gemm_qkv(const bf16* __restrict__ A,
                                                const bf16* __restrict__ W,
                                                const bf16* __restrict__ bias,
                                                bf16* __restrict__ out)
{
    __shared__ bf16 As[64][72];
    __shared__ bf16 Bs[64][72];
    const int tid  = threadIdx.x;
    const int wid  = tid >> 6, lane = tid & 63;
    const int quad = lane >> 4, l15 = lane & 15;
    const int nbase = blockIdx.x * 64;
    const int mbase = blockIdx.y * 64;
    const int m0 = wid * 16;

    f32x4 acc[4];
#pragma unroll
    for (int i = 0; i < 4; ++i) acc[i] = (f32x4){0.f, 0.f, 0.f, 0.f};

    for (int kt = 0; kt < E / 64; ++kt) {
        const int kb = kt * 64;
        __syncthreads();
#pragma unroll
        for (int i = 0; i < 2; ++i) {
            int slot = tid + i * 256;
            int row = slot >> 3, kg = slot & 7;
            *(uint4*)&As[row][kg * 8] = *(const uint4*)&A[(size_t)(mbase + row) * E + kb + kg * 8];
            *(uint4*)&Bs[row][kg * 8] = *(const uint4*)&W[(size_t)(nbase + row) * E + kb + kg * 8];
        }
        __syncthreads();
        bf16x8 a0 = *(bf16x8*)&As[m0 + l15][quad * 8];
        bf16x8 a1 = *(bf16x8*)&As[m0 + l15][32 + quad * 8];
#pragma unroll
        for (int nt = 0; nt < 4; ++nt) {
            bf16x8 b0 = *(bf16x8*)&Bs[nt * 16 + l15][quad * 8];
            bf16x8 b1 = *(bf16x8*)&Bs[nt * 16 + l15][32 + quad * 8];
            acc[nt] = __builtin_amdgcn_mfma_f32_16x16x32_bf16(a0, b0, acc[nt], 0, 0, 0);
            acc[nt] = __builtin_amdgcn_mfma_f32_16x16x32_bf16(a1, b1, acc[nt], 0, 0, 0);
        }
    }
#pragma unroll
    for (int nt = 0; nt < 4; ++nt) {
        int col = nbase + nt * 16 + l15;
        float bv = (float)bias[col];
#pragma unroll
        for (int r = 0; r < 4; ++r) {
            int row = mbase + m0 + quad * 4 + r;
            float v = acc[nt][r] + bv;
            int t = col >> 9, hh = (col >> 6) & 7, d = col & 63;
            if (t == 0) v *= CMUL;
            out[((size_t)t * H + hh) * S * D + (size_t)row * D + d] = (bf16)v;
        }
    }
}

// ---------------------------------------------------------------------------
// Fused flash attention, Q-tile 128 / K-tile 64, 4 waves (each owns TWO
// 16-row sub-blocks processed against one staged K/V tile -> barriers and
// staging amortized 2x). K/V via swizzled LDS with register prefetch (R8
// structure). Ps aliases Qs. exp2-domain fixed softmax, K-split.
// grid: (S/128, H, nsplit), block 256.
// ---------------------------------------------------------------------------
__global__ __launch_bounds__(256) void attn(const bf16* __restrict__ Qp,
                                            const bf16* __restrict__ Kp,
                                            const bf16* __restrict__ Vp,
                                            const unsigned long long* __restrict__ bits,
                                            float* __restrict__ Opart,
                                            float* __restrict__ Lpart,
                                            int ktper)
{
    __shared__ __align__(16) char smem[34816];
    bf16 (*Qs)[72]     = (bf16(*)[72])smem;                 // 128x72 (18432 B)
    bf16 (*Ps)[16][64] = (bf16(*)[16][64])smem;             // per-wave, aliases Qs
    bf16 (*Ks)[64]     = (bf16(*)[64])(smem + 18432);       // 64x64 swizzled
    bf16 (*Vts)[64]    = (bf16(*)[64])(smem + 26624);       // 64x64 swizzled V^T

    const int tid  = threadIdx.x;
    const int wid  = tid >> 6, lane = tid & 63;
    const int quad = lane >> 4, l15 = lane & 15;
    const int qt = blockIdx.x, h = blockIdx.y, split = blockIdx.z;
    const int qbase = qt * 128;
    const int mA = wid * 16, mB = 64 + wid * 16;
    const bf16* Qh = Qp + (size_t)h * S * D;
    const bf16* Kh = Kp + (size_t)h * S * D;
    const bf16* Vh = Vp + (size_t)h * S * D;

    const int krow0 = tid >> 3, kkg = tid & 7;
    const int krow1 = (tid + 256) >> 3;
    const int ksw0 = (kkg ^ (krow0 & 7)) * 8;
    const int ksw1 = (kkg ^ (krow1 & 7)) * 8;
    const int vt0 = (tid & 31) * 2, vd0 = (tid >> 5) * 8;

    // stage Q (128 rows)
#pragma unroll
    for (int i = 0; i < 4; ++i) {
        int slot = tid + i * 256;
        int row = slot >> 3, kg = slot & 7;
        *(uint4*)&Qs[row][kg * 8] = *(const uint4*)&Qh[(size_t)(qbase + row) * D + kg * 8];
    }
    __syncthreads();
    bf16x8 aqA0 = *(bf16x8*)&Qs[mA + l15][quad * 8];
    bf16x8 aqA1 = *(bf16x8*)&Qs[mA + l15][32 + quad * 8];
    bf16x8 aqB0 = *(bf16x8*)&Qs[mB + l15][quad * 8];
    bf16x8 aqB1 = *(bf16x8*)&Qs[mB + l15][32 + quad * 8];

    bf16x8 bl;
    {
        union { short s; bf16 b; } one; one.b = (bf16)1.0f;
        short v = (l15 == 0) ? one.s : (short)0;
#pragma unroll
        for (int j = 0; j < 8; ++j) bl[j] = v;
    }

    f32x4 oA[4], oB[4];
#pragma unroll
    for (int dt = 0; dt < 4; ++dt) {
        oA[dt] = (f32x4){0.f, 0.f, 0.f, 0.f};
        oB[dt] = (f32x4){0.f, 0.f, 0.f, 0.f};
    }
    f32x4 acclA = (f32x4){0.f, 0.f, 0.f, 0.f};
    f32x4 acclB = (f32x4){0.f, 0.f, 0.f, 0.f};

    const int kt0 = split * ktper, kt1 = kt0 + ktper;

    uint4 kq0, kq1, vq0, vq1;
    {
        const int kbase = kt0 * 64;
        kq0 = *(const uint4*)&Kh[(size_t)(kbase + krow0) * D + kkg * 8];
        kq1 = *(const uint4*)&Kh[(size_t)(kbase + krow1) * D + kkg * 8];
        vq0 = *(const uint4*)&Vh[(size_t)(kbase + vt0) * D + vd0];
        vq1 = *(const uint4*)&Vh[(size_t)(kbase + vt0 + 1) * D + vd0];
    }

    const unsigned long long* mbA = bits + (size_t)(qbase + mA + quad * 4) * 64 + kt0;
    const unsigned long long* mbB = bits + (size_t)(qbase + mB + quad * 4) * 64 + kt0;

    const int ksw_rd = (l15 & 7);               // K/V read swizzle key
    const int pkey   = ((l15 >> 1) & 7);        // Ps read swizzle key

    // one 16-row sub-block: QK -> softmax(P->LDS) -> PV + l-sum
    auto process = [&](bf16x8 a0, bf16x8 a1, const unsigned long long* mw,
                       f32x4& accl, f32x4* o) {
        f32x4 sc[4];
        {
            f32x4 z = (f32x4){0.f, 0.f, 0.f, 0.f};
#pragma unroll
            for (int nt = 0; nt < 4; ++nt) {
                bf16x8 b0 = *(bf16x8*)&Ks[nt * 16 + l15][(quad ^ ksw_rd) * 8];
                bf16x8 b1 = *(bf16x8*)&Ks[nt * 16 + l15][((quad + 4) ^ ksw_rd) * 8];
                sc[nt] = __builtin_amdgcn_mfma_f32_16x16x32_bf16(a0, b0, z, 0, 0, 0);
                sc[nt] = __builtin_amdgcn_mfma_f32_16x16x32_bf16(a1, b1, sc[nt], 0, 0, 0);
            }
        }
#pragma unroll
        for (int r = 0; r < 4; ++r) {
            unsigned long long sh = mw[r] >> l15;
            int row = quad * 4 + r;
            int key = ((row >> 1) & 7) << 3;
#pragma unroll
            for (int nt = 0; nt < 4; ++nt) {
                float p = __builtin_amdgcn_exp2f(sc[nt][r]);
                bool ok = (sh >> (nt * 16)) & 1ull;
                p = ok ? p : 0.f;
                Ps[wid][row][(nt * 16 + l15) ^ key] = (bf16)p;
            }
        }
        bf16x8 ap0 = *(bf16x8*)&Ps[wid][l15][(quad ^ pkey) * 8];
        bf16x8 ap1 = *(bf16x8*)&Ps[wid][l15][((quad + 4) ^ pkey) * 8];
        accl = __builtin_amdgcn_mfma_f32_16x16x32_bf16(ap0, bl, accl, 0, 0, 0);
        accl = __builtin_amdgcn_mfma_f32_16x16x32_bf16(ap1, bl, accl, 0, 0, 0);
#pragma unroll
        for (int dt = 0; dt < 4; ++dt) {
            bf16x8 bv0 = *(bf16x8*)&Vts[dt * 16 + l15][(quad ^ ksw_rd) * 8];
            bf16x8 bv1 = *(bf16x8*)&Vts[dt * 16 + l15][((quad + 4) ^ ksw_rd) * 8];
            o[dt] = __builtin_amdgcn_mfma_f32_16x16x32_bf16(ap0, bv0, o[dt], 0, 0, 0);
            o[dt] = __builtin_amdgcn_mfma_f32_16x16x32_bf16(ap1, bv1, o[dt], 0, 0, 0);
        }
    };

#pragma unroll 1
    for (int kt = kt0; kt < kt1; ++kt) {
        __syncthreads();   // previous tile consumed (guards Qs->Ps alias too)
        *(uint4*)&Ks[krow0][ksw0] = kq0;
        *(uint4*)&Ks[krow1][ksw1] = kq1;
        {
            const unsigned short* p0 = (const unsigned short*)&vq0;
            const unsigned short* p1 = (const unsigned short*)&vq1;
#pragma unroll
            for (int j = 0; j < 8; ++j) {
                unsigned int pk = (unsigned int)p0[j] | ((unsigned int)p1[j] << 16);
                *(unsigned int*)&Vts[vd0 + j][vt0 ^ (j * 8)] = pk;
            }
        }
        if (kt + 1 < kt1) {
            const int kb2 = (kt + 1) * 64;
            kq0 = *(const uint4*)&Kh[(size_t)(kb2 + krow0) * D + kkg * 8];
            kq1 = *(const uint4*)&Kh[(size_t)(kb2 + krow1) * D + kkg * 8];
            vq0 = *(const uint4*)&Vh[(size_t)(kb2 + vt0) * D + vd0];
            vq1 = *(const uint4*)&Vh[(size_t)(kb2 + vt0 + 1) * D + vd0];
        }
        unsigned long long mwA[4], mwB[4];
#pragma unroll
        for (int r = 0; r < 4; ++r) {
            mwA[r] = mbA[r * 64];
            mwB[r] = mbB[r * 64];
        }
        ++mbA; ++mbB;
        __syncthreads();   // K/V tile visible

        process(aqA0, aqA1, mwA, acclA, oA);
        process(aqB0, aqB1, mwB, acclB, oB);
    }

    // epilogue: fp32 partials for both sub-blocks
    float* Op = Opart + (size_t)(split * H + h) * S * D;
    float* Lp = Lpart + (size_t)(split * H + h) * S;
#pragma unroll
    for (int r = 0; r < 4; ++r) {
        int rowA = qbase + mA + quad * 4 + r;
        int rowB = qbase + mB + quad * 4 + r;
        if (l15 == 0) { Lp[rowA] = acclA[r]; Lp[rowB] = acclB[r]; }
#pragma unroll
        for (int dt = 0; dt < 4; ++dt) {
            Op[(size_t)rowA * D + dt * 16 + l15] = oA[dt][r];
            Op[(size_t)rowB * D + dt * 16 + l15] = oB[dt][r];
        }
    }
}

// ---------------------------------------------------------------------------
// Output GEMM with fused K-split combine: A[row][c] = (sum_s Opart)/(sum_s L)
// normalized to bf16 during LDS staging (head = K-tile index since c=kt*64+d).
// out = A @ Wo^T + bo, fp32 into d_out. grid (8, 64), block 256.
// ---------------------------------------------------------------------------
__global__ __launch_bounds__(256) void gemm_out(const float* __restrict__ Opart,
                                                const float* __restrict__ Lpart,
                                                const bf16* __restrict__ W,
                                                const bf16* __restrict__ bias,
                                                float* __restrict__ out, int nsplit)
{
    __shared__ bf16 As[64][72];
    __shared__ bf16 Bs[64][72];
    const int tid  = threadIdx.x;
    const int wid  = tid >> 6, lane = tid & 63;
    const int quad = lane >> 4, l15 = lane & 15;
    const int nbase = blockIdx.x * 64;
    const int mbase = blockIdx.y * 64;
    const int m0 = wid * 16;
    const size_t oh = (size_t)H * S * D;

    f32x4 acc[4];
#pragma unroll
    for (int i = 0; i < 4; ++i) acc[i] = (f32x4){0.f, 0.f, 0.f, 0.f};

    for (int kt = 0; kt < E / 64; ++kt) {
        const int kb = kt * 64;
        const int h = kt;                    // head index for this K-tile
        __syncthreads();
#pragma unroll
        for (int i = 0; i < 2; ++i) {
            int slot = tid + i * 256;
            int row = slot >> 3, kg = slot & 7;
            int qrow = mbase + row;
            size_t base = ((size_t)h * S + qrow) * D + kg * 8;
            float a[8] = {0, 0, 0, 0, 0, 0, 0, 0};
            float l = 0.f;
            for (int s = 0; s < nsplit; ++s) {
                float4 p0 = *(const float4*)(Opart + (size_t)s * oh + base);
                float4 p1 = *(const float4*)(Opart + (size_t)s * oh + base + 4);
                a[0] += p0.x; a[1] += p0.y; a[2] += p0.z; a[3] += p0.w;
                a[4] += p1.x; a[5] += p1.y; a[6] += p1.z; a[7] += p1.w;
                l += Lpart[(size_t)s * H * S + (size_t)h * S + qrow];
            }
            float inv = (l > 0.f) ? 1.f / l : 0.f;
            union { bf16 hh[8]; uint4 u; } cv;
#pragma unroll
            for (int j = 0; j < 8; ++j) cv.hh[j] = (bf16)(a[j] * inv);
            *(uint4*)&As[row][kg * 8] = cv.u;
            *(uint4*)&Bs[row][kg * 8] = *(const uint4*)&W[(size_t)(nbase + row) * E + kb + kg * 8];
        }
        __syncthreads();
        bf16x8 a0 = *(bf16x8*)&As[m0 + l15][quad * 8];
        bf16x8 a1 = *(bf16x8*)&As[m0 + l15][32 + quad * 8];
#pragma unroll
        for (int nt = 0; nt < 4; ++nt) {
            bf16x8 b0 = *(bf16x8*)&Bs[nt * 16 + l15][quad * 8];
            bf16x8 b1 = *(bf16x8*)&Bs[nt * 16 + l15][32 + quad * 8];
            acc[nt] = __builtin_amdgcn_mfma_f32_16x16x32_bf16(a0, b0, acc[nt], 0, 0, 0);
            acc[nt] = __builtin_amdgcn_mfma_f32_16x16x32_bf16(a1, b1, acc[nt], 0, 0, 0);
        }
    }
#pragma unroll
    for (int nt = 0; nt < 4; ++nt) {
        int col = nbase + nt * 16 + l15;
        float bv = (float)bias[col];
#pragma unroll
        for (int r = 0; r < 4; ++r) {
            int row = mbase + m0 + quad * 4 + r;
            out[(size_t)row * E + col] = acc[nt][r] + bv;
        }
    }
}

// ---------------------------------------------------------------------------
extern "C" void kernel_launch(void* const* d_in, const int* in_sizes, int n_in,
                              void* d_out, int out_size, void* d_ws, size_t ws_size,
                              hipStream_t stream)
{
    char* ws = (char*)d_ws;
    const size_t MB = (size_t)1 << 20;
    bf16* Qw   = (bf16*)(ws + 0 * MB);        // 12 MB: Q|K|V planar cat
    bf16* Kw   = (bf16*)(ws + 4 * MB);
    bf16* Vw   = (bf16*)(ws + 8 * MB);
    unsigned long long* bits = (unsigned long long*)(ws + 16 * MB); // 2 MB
    bf16* xb   = (bf16*)(ws + 18 * MB);       // 4 MB
    bf16* Wcat = (bf16*)(ws + 22 * MB);       // 1.5 MB
    bf16* Wob  = (bf16*)(ws + 24 * MB);       // 0.5 MB
    bf16* bcat = (bf16*)(ws + 25 * MB);
    bf16* bob  = (bf16*)(ws + 25 * MB + 8192);
    float* Opart = (float*)(ws + 26 * MB);    // nsplit x 8 MB

    int nsplit = (ws_size >= 59 * MB) ? 4 : 2;
    int ktper  = (S / 64) / nsplit;
    float* Lpart = (float*)(ws + 26 * MB + (size_t)nsplit * 8 * MB);

    hipLaunchKernelGGL(prep, dim3(2048), dim3(256), 0, stream,
                       d_in[9], bits,
                       (const float*)d_in[0], (const float*)d_in[1],
                       (const float*)d_in[3], (const float*)d_in[5],
                       (const float*)d_in[7], (const float*)d_in[2],
                       (const float*)d_in[4], (const float*)d_in[6],
                       (const float*)d_in[8],
                       xb, Wcat, Wob, bcat, bob);
    hipLaunchKernelGGL(gemm_qkv, dim3(24, 64), dim3(256), 0, stream,
                       xb, Wcat, bcat, Qw);
    hipLaunchKernelGGL(attn, dim3(S / 128, H, nsplit), dim3(256), 0, stream,
                       Qw, Kw, Vw, bits, Opart, Lpart, ktper);
    hipLaunchKernelGGL(gemm_out, dim3(8, 64), dim3(256), 0, stream,
                       Opart, Lpart, Wob, bob, (float*)d_out, nsplit);
}

// Round 13
// 306.435 us; speedup vs baseline: 1.3476x; 1.0203x over previous
//
#include <hip/hip_runtime.h>
#include <hip/hip_bf16.h>
#include <stdint.h>

#define S 4096
#define E 512
#define H 8
#define D 64
#define MROW 5000        // mask row stride (MAX_GENES)

typedef __hip_bfloat16 bf16;
typedef __attribute__((ext_vector_type(8))) short bf16x8;
typedef __attribute__((ext_vector_type(4))) float f32x4;

#define CMUL (0.125f * 1.4426950408889634f)  // scale * log2(e), folded into Q

// ---------------------------------------------------------------------------
// prep: all 2048 blocks convert fp32->bf16 (12 MB), then pack mask (100 MB)
// into TRANSPOSED bit matrix bitsT[word][row] (coalesced write AND read).
// ---------------------------------------------------------------------------
__global__ __launch_bounds__(256) void prep(
    const void* __restrict__ mask, unsigned long long* __restrict__ bitsT,
    const float* __restrict__ x,  const float* __restrict__ wq,
    const float* __restrict__ wk, const float* __restrict__ wv,
    const float* __restrict__ wo, const float* __restrict__ bq,
    const float* __restrict__ bk, const float* __restrict__ bv,
    const float* __restrict__ bo,
    bf16* __restrict__ xb, bf16* __restrict__ wcat, bf16* __restrict__ wob,
    bf16* __restrict__ bcat, bf16* __restrict__ bob)
{
    const int tid = threadIdx.x;
    const int b   = blockIdx.x;
    // --- convert (grid-stride over all blocks) ---
    {
        const float* srcs[9] = {x, wq, wk, wv, wo, bq, bk, bv, bo};
        bf16* dsts[9] = {xb, wcat, wcat + 262144, wcat + 524288, wob,
                         bcat, bcat + 512, bcat + 1024, bob};
        const int cnts[9] = {2097152, 262144, 262144, 262144, 262144,
                             512, 512, 512, 512};
        const int ngroups = (2097152 + 4 * 262144 + 4 * 512) / 4;
        for (int g = b * 256 + tid; g < ngroups; g += 2048 * 256) {
            int e = g * 4;
            int seg = 0;
            while (e >= cnts[seg]) { e -= cnts[seg]; ++seg; }
            float4 v = *(const float4*)(srcs[seg] + e);
            union { bf16 h[4]; uint2 u; } cv;
            cv.h[0] = (bf16)v.x; cv.h[1] = (bf16)v.y;
            cv.h[2] = (bf16)v.z; cv.h[3] = (bf16)v.w;
            *(uint2*)(dsts[seg] + e) = cv.u;
        }
    }
    // --- pack mask (transposed); per-wave dtype flag from first 512 words ---
    {
        const unsigned int* mw32 = (const unsigned int*)mask;
        int lane = tid & 63;
        int hit = 0;
#pragma unroll
        for (int i = 0; i < 8; ++i) {
            unsigned int w = mw32[lane + i * 64];
            if (w > 1u && (w & 0xFEFEFEFEu) == 0u) hit = 1;
        }
        const bool isbyte = (__ballot(hit) != 0ull);
        int wid  = (b * 256 + tid) >> 6;
        int nwav = (2048 * 256) >> 6;
        int total = (S / 64) * S;
        for (int w = wid; w < total; w += nwav) {
            int word = w >> 12;          // 0..63
            int row  = w & (S - 1);      // 0..4095
            int col  = word * 64 + lane;
            unsigned int v;
            if (isbyte) v = ((const unsigned char*)mask)[(size_t)row * MROW + col];
            else        v = ((const unsigned int*)mask)[(size_t)row * MROW + col];
            unsigned long long bb = __ballot(v != 0u);
            if (lane == 0) bitsT[(size_t)word * S + row] = bb;
        }
    }
}

// ---------------------------------------------------------------------------
// QKV GEMM: C(64x64 tile) = A(Mx512) @ W^T + bias, N=1536 fused.
// out planar Q|K|V, each [h][s][64] bf16; Q pre-scaled by CMUL.
// ---------------------------------------------------------------------------
__global__ __launch_bounds__(256) void gemm_qkv(const bf16* __restrict__ A,
                                                const bf16* __restrict__ W,
                                                const bf16* __restrict__ bias,
                                                bf16* __restrict__ out)
{
    __shared__ bf16 As[64][72];
    __shared__ bf16 Bs[64][72];
    const int tid  = threadIdx.x;
    const int wid  = tid >> 6, lane = tid & 63;
    const int quad = lane >> 4, l15 = lane & 15;
    const int nbase = blockIdx.x * 64;
    const int mbase = blockIdx.y * 64;
    const int m0 = wid * 16;

    f32x4 acc[4];
#pragma unroll
    for (int i = 0; i < 4; ++i) acc[i] = (f32x4){0.f, 0.f, 0.f, 0.f};

    for (int kt = 0; kt < E / 64; ++kt) {
        const int kb = kt * 64;
        __syncthreads();
#pragma unroll
        for (int i = 0; i < 2; ++i) {
            int slot = tid + i * 256;
            int row = slot >> 3, kg = slot & 7;
            *(uint4*)&As[row][kg * 8] = *(const uint4*)&A[(size_t)(mbase + row) * E + kb + kg * 8];
            *(uint4*)&Bs[row][kg * 8] = *(const uint4*)&W[(size_t)(nbase + row) * E + kb + kg * 8];
        }
        __syncthreads();
        bf16x8 a0 = *(bf16x8*)&As[m0 + l15][quad * 8];
        bf16x8 a1 = *(bf16x8*)&As[m0 + l15][32 + quad * 8];
#pragma unroll
        for (int nt = 0; nt < 4; ++nt) {
            bf16x8 b0 = *(bf16x8*)&Bs[nt * 16 + l15][quad * 8];
            bf16x8 b1 = *(bf16x8*)&Bs[nt * 16 + l15][32 + quad * 8];
            acc[nt] = __builtin_amdgcn_mfma_f32_16x16x32_bf16(a0, b0, acc[nt], 0, 0, 0);
            acc[nt] = __builtin_amdgcn_mfma_f32_16x16x32_bf16(a1, b1, acc[nt], 0, 0, 0);
        }
    }
#pragma unroll
    for (int nt = 0; nt < 4; ++nt) {
        int col = nbase + nt * 16 + l15;
        float bv = (float)bias[col];
#pragma unroll
        for (int r = 0; r < 4; ++r) {
            int row = mbase + m0 + quad * 4 + r;
            float v = acc[nt][r] + bv;
            int t = col >> 9, hh = (col >> 6) & 7, d = col & 63;
            if (t == 0) v *= CMUL;
            out[((size_t)t * H + hh) * S * D + (size_t)row * D + d] = (bf16)v;
        }
    }
}

// ---------------------------------------------------------------------------
// Fused flash attention with OPERAND-SWAPPED QK: sc = mfma(K_frag, Q_frag)
// gives P^T C-layout (lane = query, 4 consecutive tokens per nt) so the
// P round-trip is 4x ds_write_b64 (packed) instead of 16x ds_write_b16, the
// mask is ONE coalesced 8B load/lane from transposed bitsT, and Q needs no
// LDS (lane=query reads its row direct from global once). PV side unchanged.
// K/V staged via swizzled LDS with register prefetch (R8 structure).
// grid: (S/64, H, nsplit), block 256 (4 waves x 16 q-rows).
// ---------------------------------------------------------------------------
__global__ __launch_bounds__(256) void attn(const bf16* __restrict__ Qp,
                                            const bf16* __restrict__ Kp,
                                            const bf16* __restrict__ Vp,
                                            const unsigned long long* __restrict__ bitsT,
                                            float* __restrict__ Opart,
                                            float* __restrict__ Lpart,
                                            int ktper)
{
    __shared__ __align__(16) char smem[25600];
    bf16 (*Ps)[16][72] = (bf16(*)[16][72])smem;             // 4 x 16q x 64t (+pad)
    bf16 (*Ks)[64]     = (bf16(*)[64])(smem + 9216);        // 64x64 swizzled
    bf16 (*Vts)[64]    = (bf16(*)[64])(smem + 17408);       // 64x64 swizzled V^T

    const int tid  = threadIdx.x;
    const int wid  = tid >> 6, lane = tid & 63;
    const int quad = lane >> 4, l15 = lane & 15;
    const int qt = blockIdx.x, h = blockIdx.y, split = blockIdx.z;
    const int qbase = qt * 64;
    const int m0 = wid * 16;
    const bf16* Qh = Qp + (size_t)h * S * D;
    const bf16* Kh = Kp + (size_t)h * S * D;
    const bf16* Vh = Vp + (size_t)h * S * D;

    const int krow0 = tid >> 3, kkg = tid & 7;
    const int krow1 = (tid + 256) >> 3;
    const int ksw0 = (kkg ^ (krow0 & 7)) * 8;
    const int ksw1 = (kkg ^ (krow1 & 7)) * 8;
    const int vt0 = (tid & 31) * 2, vd0 = (tid >> 5) * 8;

    // Q fragments direct from global: lane = query row (B-operand layout)
    const bf16* qrow = Qh + (size_t)(qbase + m0 + l15) * D;
    bf16x8 aq0 = *(const bf16x8*)(qrow + quad * 8);
    bf16x8 aq1 = *(const bf16x8*)(qrow + 32 + quad * 8);

    // ones B-fragment for l-sum MFMA (col 0 only)
    bf16x8 bl;
    {
        union { short s; bf16 b; } one; one.b = (bf16)1.0f;
        short v = (l15 == 0) ? one.s : (short)0;
#pragma unroll
        for (int j = 0; j < 8; ++j) bl[j] = v;
    }

    f32x4 o[4];
#pragma unroll
    for (int dt = 0; dt < 4; ++dt) o[dt] = (f32x4){0.f, 0.f, 0.f, 0.f};
    f32x4 accl = (f32x4){0.f, 0.f, 0.f, 0.f};

    const int kt0 = split * ktper, kt1 = kt0 + ktper;

    uint4 kq0, kq1, vq0, vq1;
    {
        const int kbase = kt0 * 64;
        kq0 = *(const uint4*)&Kh[(size_t)(kbase + krow0) * D + kkg * 8];
        kq1 = *(const uint4*)&Kh[(size_t)(kbase + krow1) * D + kkg * 8];
        vq0 = *(const uint4*)&Vh[(size_t)(kbase + vt0) * D + vd0];
        vq1 = *(const uint4*)&Vh[(size_t)(kbase + vt0 + 1) * D + vd0];
    }

    // transposed mask: one 8B word per lane (query = qbase+m0+l15), coalesced
    const unsigned long long* mb = bitsT + (size_t)kt0 * S + qbase + m0 + l15;

    const int ksw_rd = (l15 & 7);               // K/V read swizzle key
#pragma unroll 1
    for (int kt = kt0; kt < kt1; ++kt) {
        __syncthreads();   // previous tile consumed
        *(uint4*)&Ks[krow0][ksw0] = kq0;
        *(uint4*)&Ks[krow1][ksw1] = kq1;
        {
            const unsigned short* p0 = (const unsigned short*)&vq0;
            const unsigned short* p1 = (const unsigned short*)&vq1;
#pragma unroll
            for (int j = 0; j < 8; ++j) {
                unsigned int pk = (unsigned int)p0[j] | ((unsigned int)p1[j] << 16);
                *(unsigned int*)&Vts[vd0 + j][vt0 ^ (j * 8)] = pk;
            }
        }
        if (kt + 1 < kt1) {
            const int kb2 = (kt + 1) * 64;
            kq0 = *(const uint4*)&Kh[(size_t)(kb2 + krow0) * D + kkg * 8];
            kq1 = *(const uint4*)&Kh[(size_t)(kb2 + krow1) * D + kkg * 8];
            vq0 = *(const uint4*)&Vh[(size_t)(kb2 + vt0) * D + vd0];
            vq1 = *(const uint4*)&Vh[(size_t)(kb2 + vt0 + 1) * D + vd0];
        }
        unsigned long long mw = *mb;
        mb += S;
        __syncthreads();   // K/V tile visible

        // S^T = K Q^T (exp2 domain): A = K frag (lane=token), B = Q frag
        f32x4 sc[4];
        {
            f32x4 z = (f32x4){0.f, 0.f, 0.f, 0.f};
#pragma unroll
            for (int nt = 0; nt < 4; ++nt) {
                bf16x8 kb0 = *(bf16x8*)&Ks[nt * 16 + l15][(quad ^ ksw_rd) * 8];
                bf16x8 kb1 = *(bf16x8*)&Ks[nt * 16 + l15][((quad + 4) ^ ksw_rd) * 8];
                sc[nt] = __builtin_amdgcn_mfma_f32_16x16x32_bf16(kb0, aq0, z, 0, 0, 0);
                sc[nt] = __builtin_amdgcn_mfma_f32_16x16x32_bf16(kb1, aq1, sc[nt], 0, 0, 0);
            }
        }
        // lane holds P^T: query=l15, tokens nt*16+quad*4+{0..3} (consecutive!)
        // p = exp2(s) masked; 4 packed bf16 -> one ds_write_b64 per nt.
        unsigned long long sh = mw >> (quad * 4);
#pragma unroll
        for (int nt = 0; nt < 4; ++nt) {
            unsigned int wb = (unsigned int)(sh >> (nt * 16)) & 0xFu;
            union { bf16 hh[4]; uint2 u; } pk;
#pragma unroll
            for (int r = 0; r < 4; ++r) {
                float p = __builtin_amdgcn_exp2f(sc[nt][r]);
                p = (wb >> r) & 1u ? p : 0.f;
                pk.hh[r] = (bf16)p;
            }
            *(uint2*)&Ps[wid][l15][nt * 16 + quad * 4] = pk.u;
        }
        // O += P V ; l += P 1   (P A-frag: row l15, contiguous tokens)
        bf16x8 ap0 = *(bf16x8*)&Ps[wid][l15][quad * 8];
        bf16x8 ap1 = *(bf16x8*)&Ps[wid][l15][32 + quad * 8];
        accl = __builtin_amdgcn_mfma_f32_16x16x32_bf16(ap0, bl, accl, 0, 0, 0);
        accl = __builtin_amdgcn_mfma_f32_16x16x32_bf16(ap1, bl, accl, 0, 0, 0);
#pragma unroll
        for (int dt = 0; dt < 4; ++dt) {
            bf16x8 bv0 = *(bf16x8*)&Vts[dt * 16 + l15][(quad ^ ksw_rd) * 8];
            bf16x8 bv1 = *(bf16x8*)&Vts[dt * 16 + l15][((quad + 4) ^ ksw_rd) * 8];
            o[dt] = __builtin_amdgcn_mfma_f32_16x16x32_bf16(ap0, bv0, o[dt], 0, 0, 0);
            o[dt] = __builtin_amdgcn_mfma_f32_16x16x32_bf16(ap1, bv1, o[dt], 0, 0, 0);
        }
    }
    // epilogue: fp32 partials; O/l C-layout rows = quad*4+r (same as before)
    float* Op = Opart + (size_t)(split * H + h) * S * D;
    float* Lp = Lpart + (size_t)(split * H + h) * S;
#pragma unroll
    for (int r = 0; r < 4; ++r) {
        int row = qbase + m0 + quad * 4 + r;
        if (l15 == 0) Lp[row] = accl[r];
#pragma unroll
        for (int dt = 0; dt < 4; ++dt)
            Op[(size_t)row * D + dt * 16 + l15] = o[dt][r];
    }
}

// ---------------------------------------------------------------------------
// Output GEMM with fused K-split combine: A[row][c] = (sum_s Opart)/(sum_s L)
// normalized to bf16 during LDS staging (head = K-tile index since c=kt*64+d).
// out = A @ Wo^T + bo, fp32 into d_out. grid (8, 64), block 256.
// ---------------------------------------------------------------------------
__global__ __launch_bounds__(256) void gemm_out(const float* __restrict__ Opart,
                                                const float* __restrict__ Lpart,
                                                const bf16* __restrict__ W,
                                                const bf16* __restrict__ bias,
                                                float* __restrict__ out, int nsplit)
{
    __shared__ bf16 As[64][72];
    __shared__ bf16 Bs[64][72];
    const int tid  = threadIdx.x;
    const int wid  = tid >> 6, lane = tid & 63;
    const int quad = lane >> 4, l15 = lane & 15;
    const int nbase = blockIdx.x * 64;
    const int mbase = blockIdx.y * 64;
    const int m0 = wid * 16;
    const size_t oh = (size_t)H * S * D;

    f32x4 acc[4];
#pragma unroll
    for (int i = 0; i < 4; ++i) acc[i] = (f32x4){0.f, 0.f, 0.f, 0.f};

    for (int kt = 0; kt < E / 64; ++kt) {
        const int kb = kt * 64;
        const int h = kt;                    // head index for this K-tile
        __syncthreads();
#pragma unroll
        for (int i = 0; i < 2; ++i) {
            int slot = tid + i * 256;
            int row = slot >> 3, kg = slot & 7;
            int qrow = mbase + row;
            size_t base = ((size_t)h * S + qrow) * D + kg * 8;
            float a[8] = {0, 0, 0, 0, 0, 0, 0, 0};
            float l = 0.f;
            for (int s = 0; s < nsplit; ++s) {
                float4 p0 = *(const float4*)(Opart + (size_t)s * oh + base);
                float4 p1 = *(const float4*)(Opart + (size_t)s * oh + base + 4);
                a[0] += p0.x; a[1] += p0.y; a[2] += p0.z; a[3] += p0.w;
                a[4] += p1.x; a[5] += p1.y; a[6] += p1.z; a[7] += p1.w;
                l += Lpart[(size_t)s * H * S + (size_t)h * S + qrow];
            }
            float inv = (l > 0.f) ? 1.f / l : 0.f;
            union { bf16 hh[8]; uint4 u; } cv;
#pragma unroll
            for (int j = 0; j < 8; ++j) cv.hh[j] = (bf16)(a[j] * inv);
            *(uint4*)&As[row][kg * 8] = cv.u;
            *(uint4*)&Bs[row][kg * 8] = *(const uint4*)&W[(size_t)(nbase + row) * E + kb + kg * 8];
        }
        __syncthreads();
        bf16x8 a0 = *(bf16x8*)&As[m0 + l15][quad * 8];
        bf16x8 a1 = *(bf16x8*)&As[m0 + l15][32 + quad * 8];
#pragma unroll
        for (int nt = 0; nt < 4; ++nt) {
            bf16x8 b0 = *(bf16x8*)&Bs[nt * 16 + l15][quad * 8];
            bf16x8 b1 = *(bf16x8*)&Bs[nt * 16 + l15][32 + quad * 8];
            acc[nt] = __builtin_amdgcn_mfma_f32_16x16x32_bf16(a0, b0, acc[nt], 0, 0, 0);
            acc[nt] = __builtin_amdgcn_mfma_f32_16x16x32_bf16(a1, b1, acc[nt], 0, 0, 0);
        }
    }
#pragma unroll
    for (int nt = 0; nt < 4; ++nt) {
        int col = nbase + nt * 16 + l15;
        float bv = (float)bias[col];
#pragma unroll
        for (int r = 0; r < 4; ++r) {
            int row = mbase + m0 + quad * 4 + r;
            out[(size_t)row * E + col] = acc[nt][r] + bv;
        }
    }
}

// ---------------------------------------------------------------------------
extern "C" void kernel_launch(void* const* d_in, const int* in_sizes, int n_in,
                              void* d_out, int out_size, void* d_ws, size_t ws_size,
                              hipStream_t stream)
{
    char* ws = (char*)d_ws;
    const size_t MB = (size_t)1 << 20;
    bf16* Qw   = (bf16*)(ws + 0 * MB);        // 12 MB: Q|K|V planar cat
    bf16* Kw   = (bf16*)(ws + 4 * MB);
    bf16* Vw   = (bf16*)(ws + 8 * MB);
    unsigned long long* bitsT = (unsigned long long*)(ws + 16 * MB); // 2 MB
    bf16* xb   = (bf16*)(ws + 18 * MB);       // 4 MB
    bf16* Wcat = (bf16*)(ws + 22 * MB);       // 1.5 MB
    bf16* Wob  = (bf16*)(ws + 24 * MB);       // 0.5 MB
    bf16* bcat = (bf16*)(ws + 25 * MB);
    bf16* bob  = (bf16*)(ws + 25 * MB + 8192);
    float* Opart = (float*)(ws + 26 * MB);    // nsplit x 8 MB

    int nsplit = (ws_size >= 59 * MB) ? 4 : 2;
    int ktper  = (S / 64) / nsplit;
    float* Lpart = (float*)(ws + 26 * MB + (size_t)nsplit * 8 * MB);

    hipLaunchKernelGGL(prep, dim3(2048), dim3(256), 0, stream,
                       d_in[9], bitsT,
                       (const float*)d_in[0], (const float*)d_in[1],
                       (const float*)d_in[3], (const float*)d_in[5],
                       (const float*)d_in[7], (const float*)d_in[2],
                       (const float*)d_in[4], (const float*)d_in[6],
                       (const float*)d_in[8],
                       xb, Wcat, Wob, bcat, bob);
    hipLaunchKernelGGL(gemm_qkv, dim3(24, 64), dim3(256), 0, stream,
                       xb, Wcat, bcat, Qw);
    hipLaunchKernelGGL(attn, dim3(S / 64, H, nsplit), dim3(256), 0, stream,
                       Qw, Kw, Vw, bitsT, Opart, Lpart, ktper);
    hipLaunchKernelGGL(gemm_out, dim3(8, 64), dim3(256), 0, stream,
                       Opart, Lpart, Wob, bob, (float*)d_out, nsplit);
}

// Round 14
// 304.905 us; speedup vs baseline: 1.3544x; 1.0050x over previous
//
#include <hip/hip_runtime.h>
#include <hip/hip_bf16.h>
#include <stdint.h>

#define S 4096
#define E 512
#define H 8
#define D 64
#define MROW 5000        // mask row stride (MAX_GENES)

typedef __hip_bfloat16 bf16;
typedef __attribute__((ext_vector_type(8))) short bf16x8;
typedef __attribute__((ext_vector_type(4))) float f32x4;

#define CMUL (0.125f * 1.4426950408889634f)  // scale * log2(e), folded into Q

// ---------------------------------------------------------------------------
// prep: all 2048 blocks convert fp32->bf16 (12 MB), then pack mask (100 MB)
// into TRANSPOSED bit matrix bitsT[word][row] (coalesced write AND read).
// ---------------------------------------------------------------------------
__global__ __launch_bounds__(256) void prep(
    const void* __restrict__ mask, unsigned long long* __restrict__ bitsT,
    const float* __restrict__ x,  const float* __restrict__ wq,
    const float* __restrict__ wk, const float* __restrict__ wv,
    const float* __restrict__ wo, const float* __restrict__ bq,
    const float* __restrict__ bk, const float* __restrict__ bv,
    const float* __restrict__ bo,
    bf16* __restrict__ xb, bf16* __restrict__ wcat, bf16* __restrict__ wob,
    bf16* __restrict__ bcat, bf16* __restrict__ bob)
{
    const int tid = threadIdx.x;
    const int b   = blockIdx.x;
    {
        const float* srcs[9] = {x, wq, wk, wv, wo, bq, bk, bv, bo};
        bf16* dsts[9] = {xb, wcat, wcat + 262144, wcat + 524288, wob,
                         bcat, bcat + 512, bcat + 1024, bob};
        const int cnts[9] = {2097152, 262144, 262144, 262144, 262144,
                             512, 512, 512, 512};
        const int ngroups = (2097152 + 4 * 262144 + 4 * 512) / 4;
        for (int g = b * 256 + tid; g < ngroups; g += 2048 * 256) {
            int e = g * 4;
            int seg = 0;
            while (e >= cnts[seg]) { e -= cnts[seg]; ++seg; }
            float4 v = *(const float4*)(srcs[seg] + e);
            union { bf16 h[4]; uint2 u; } cv;
            cv.h[0] = (bf16)v.x; cv.h[1] = (bf16)v.y;
            cv.h[2] = (bf16)v.z; cv.h[3] = (bf16)v.w;
            *(uint2*)(dsts[seg] + e) = cv.u;
        }
    }
    {
        const unsigned int* mw32 = (const unsigned int*)mask;
        int lane = tid & 63;
        int hit = 0;
#pragma unroll
        for (int i = 0; i < 8; ++i) {
            unsigned int w = mw32[lane + i * 64];
            if (w > 1u && (w & 0xFEFEFEFEu) == 0u) hit = 1;
        }
        const bool isbyte = (__ballot(hit) != 0ull);
        int wid  = (b * 256 + tid) >> 6;
        int nwav = (2048 * 256) >> 6;
        int total = (S / 64) * S;
        for (int w = wid; w < total; w += nwav) {
            int word = w >> 12;          // 0..63
            int row  = w & (S - 1);      // 0..4095
            int col  = word * 64 + lane;
            unsigned int v;
            if (isbyte) v = ((const unsigned char*)mask)[(size_t)row * MROW + col];
            else        v = ((const unsigned int*)mask)[(size_t)row * MROW + col];
            unsigned long long bb = __ballot(v != 0u);
            if (lane == 0) bitsT[(size_t)word * S + row] = bb;
        }
    }
}

// ---------------------------------------------------------------------------
// QKV GEMM: C(64x64 tile) = A(Mx512) @ W^T + bias, N=1536 fused.
// out planar Q|K|V, each [h][s][64] bf16; Q pre-scaled by CMUL.
// ---------------------------------------------------------------------------
__global__ __launch_bounds__(256) void gemm_qkv(const bf16* __restrict__ A,
                                                const bf16* __restrict__ W,
                                                const bf16* __restrict__ bias,
                                                bf16* __restrict__ out)
{
    __shared__ bf16 As[64][72];
    __shared__ bf16 Bs[64][72];
    const int tid  = threadIdx.x;
    const int wid  = tid >> 6, lane = tid & 63;
    const int quad = lane >> 4, l15 = lane & 15;
    const int nbase = blockIdx.x * 64;
    const int mbase = blockIdx.y * 64;
    const int m0 = wid * 16;

    f32x4 acc[4];
#pragma unroll
    for (int i = 0; i < 4; ++i) acc[i] = (f32x4){0.f, 0.f, 0.f, 0.f};

    for (int kt = 0; kt < E / 64; ++kt) {
        const int kb = kt * 64;
        __syncthreads();
#pragma unroll
        for (int i = 0; i < 2; ++i) {
            int slot = tid + i * 256;
            int row = slot >> 3, kg = slot & 7;
            *(uint4*)&As[row][kg * 8] = *(const uint4*)&A[(size_t)(mbase + row) * E + kb + kg * 8];
            *(uint4*)&Bs[row][kg * 8] = *(const uint4*)&W[(size_t)(nbase + row) * E + kb + kg * 8];
        }
        __syncthreads();
        bf16x8 a0 = *(bf16x8*)&As[m0 + l15][quad * 8];
        bf16x8 a1 = *(bf16x8*)&As[m0 + l15][32 + quad * 8];
#pragma unroll
        for (int nt = 0; nt < 4; ++nt) {
            bf16x8 b0 = *(bf16x8*)&Bs[nt * 16 + l15][quad * 8];
            bf16x8 b1 = *(bf16x8*)&Bs[nt * 16 + l15][32 + quad * 8];
            acc[nt] = __builtin_amdgcn_mfma_f32_16x16x32_bf16(a0, b0, acc[nt], 0, 0, 0);
            acc[nt] = __builtin_amdgcn_mfma_f32_16x16x32_bf16(a1, b1, acc[nt], 0, 0, 0);
        }
    }
#pragma unroll
    for (int nt = 0; nt < 4; ++nt) {
        int col = nbase + nt * 16 + l15;
        float bv = (float)bias[col];
#pragma unroll
        for (int r = 0; r < 4; ++r) {
            int row = mbase + m0 + quad * 4 + r;
            float v = acc[nt][r] + bv;
            int t = col >> 9, hh = (col >> 6) & 7, d = col & 63;
            if (t == 0) v *= CMUL;
            out[((size_t)t * H + hh) * S * D + (size_t)row * D + d] = (bf16)v;
        }
    }
}

// ---------------------------------------------------------------------------
// Fused flash attention, operand-swapped QK (P^T layout), VALU-dieted softmax:
// mask applied pre-exp2 (score -> -200 => exp2 == 0), bf16 conversion via
// round-half-up add + v_perm pair-pack (no software RNE), V-transpose via
// v_perm. K/V via swizzled LDS + register prefetch. One 8B coalesced mask
// load per lane from transposed bitsT. grid: (S/64, H, nsplit), block 256.
// ---------------------------------------------------------------------------
__global__ __launch_bounds__(256) void attn(const bf16* __restrict__ Qp,
                                            const bf16* __restrict__ Kp,
                                            const bf16* __restrict__ Vp,
                                            const unsigned long long* __restrict__ bitsT,
                                            float* __restrict__ Opart,
                                            float* __restrict__ Lpart,
                                            int ktper)
{
    __shared__ __align__(16) char smem[25600];
    bf16 (*Ps)[16][72] = (bf16(*)[16][72])smem;             // 4 x 16q x 64t (+pad)
    bf16 (*Ks)[64]     = (bf16(*)[64])(smem + 9216);        // 64x64 swizzled
    bf16 (*Vts)[64]    = (bf16(*)[64])(smem + 17408);       // 64x64 swizzled V^T

    const int tid  = threadIdx.x;
    const int wid  = tid >> 6, lane = tid & 63;
    const int quad = lane >> 4, l15 = lane & 15;
    const int qt = blockIdx.x, h = blockIdx.y, split = blockIdx.z;
    const int qbase = qt * 64;
    const int m0 = wid * 16;
    const bf16* Qh = Qp + (size_t)h * S * D;
    const bf16* Kh = Kp + (size_t)h * S * D;
    const bf16* Vh = Vp + (size_t)h * S * D;

    const int krow0 = tid >> 3, kkg = tid & 7;
    const int krow1 = (tid + 256) >> 3;
    const int ksw0 = (kkg ^ (krow0 & 7)) * 8;
    const int ksw1 = (kkg ^ (krow1 & 7)) * 8;
    const int vt0 = (tid & 31) * 2, vd0 = (tid >> 5) * 8;

    // Q fragments direct from global: lane = query row (B-operand layout)
    const bf16* qrow = Qh + (size_t)(qbase + m0 + l15) * D;
    bf16x8 aq0 = *(const bf16x8*)(qrow + quad * 8);
    bf16x8 aq1 = *(const bf16x8*)(qrow + 32 + quad * 8);

    // ones B-fragment for l-sum MFMA (col 0 only)
    bf16x8 bl;
    {
        union { short s; bf16 b; } one; one.b = (bf16)1.0f;
        short v = (l15 == 0) ? one.s : (short)0;
#pragma unroll
        for (int j = 0; j < 8; ++j) bl[j] = v;
    }

    f32x4 o[4];
#pragma unroll
    for (int dt = 0; dt < 4; ++dt) o[dt] = (f32x4){0.f, 0.f, 0.f, 0.f};
    f32x4 accl = (f32x4){0.f, 0.f, 0.f, 0.f};

    const int kt0 = split * ktper, kt1 = kt0 + ktper;

    uint4 kq0, kq1, vq0, vq1;
    {
        const int kbase = kt0 * 64;
        kq0 = *(const uint4*)&Kh[(size_t)(kbase + krow0) * D + kkg * 8];
        kq1 = *(const uint4*)&Kh[(size_t)(kbase + krow1) * D + kkg * 8];
        vq0 = *(const uint4*)&Vh[(size_t)(kbase + vt0) * D + vd0];
        vq1 = *(const uint4*)&Vh[(size_t)(kbase + vt0 + 1) * D + vd0];
    }

    // transposed mask: one 8B word per lane (query = qbase+m0+l15), coalesced
    const unsigned long long* mb = bitsT + (size_t)kt0 * S + qbase + m0 + l15;

    const int ksw_rd = (l15 & 7);               // K/V read swizzle key
#pragma unroll 1
    for (int kt = kt0; kt < kt1; ++kt) {
        __syncthreads();   // previous tile consumed
        *(uint4*)&Ks[krow0][ksw0] = kq0;
        *(uint4*)&Ks[krow1][ksw1] = kq1;
        {
            const unsigned int* w0 = (const unsigned int*)&vq0;
            const unsigned int* w1 = (const unsigned int*)&vq1;
#pragma unroll
            for (int j = 0; j < 8; ++j) {
                unsigned int pk = __builtin_amdgcn_perm(
                    w1[j >> 1], w0[j >> 1],
                    (j & 1) ? 0x07060302u : 0x05040100u);
                *(unsigned int*)&Vts[vd0 + j][vt0 ^ (j * 8)] = pk;
            }
        }
        if (kt + 1 < kt1) {
            const int kb2 = (kt + 1) * 64;
            kq0 = *(const uint4*)&Kh[(size_t)(kb2 + krow0) * D + kkg * 8];
            kq1 = *(const uint4*)&Kh[(size_t)(kb2 + krow1) * D + kkg * 8];
            vq0 = *(const uint4*)&Vh[(size_t)(kb2 + vt0) * D + vd0];
            vq1 = *(const uint4*)&Vh[(size_t)(kb2 + vt0 + 1) * D + vd0];
        }
        unsigned long long mw = *mb;
        mb += S;
        __syncthreads();   // K/V tile visible

        // S^T = K Q^T (exp2 domain): A = K frag (lane=token), B = Q frag
        f32x4 sc[4];
        {
            f32x4 z = (f32x4){0.f, 0.f, 0.f, 0.f};
#pragma unroll
            for (int nt = 0; nt < 4; ++nt) {
                bf16x8 kb0 = *(bf16x8*)&Ks[nt * 16 + l15][(quad ^ ksw_rd) * 8];
                bf16x8 kb1 = *(bf16x8*)&Ks[nt * 16 + l15][((quad + 4) ^ ksw_rd) * 8];
                sc[nt] = __builtin_amdgcn_mfma_f32_16x16x32_bf16(kb0, aq0, z, 0, 0, 0);
                sc[nt] = __builtin_amdgcn_mfma_f32_16x16x32_bf16(kb1, aq1, sc[nt], 0, 0, 0);
            }
        }
        // lane holds P^T: query=l15, tokens nt*16+quad*4+{0..3}.
        // Mask pre-exp2 (-200 -> exp2==0.0); pack via +0x8000 and v_perm
        // (round-half-up bf16; common-mode bias cancels in l-normalization).
        const unsigned long long sh = mw >> (quad * 4);
        const unsigned int wlo = (unsigned int)sh;
        const unsigned int whi = (unsigned int)(sh >> 32);
#pragma unroll
        for (int nt = 0; nt < 4; ++nt) {
            const unsigned int wsel = (nt < 2) ? wlo : whi;
            unsigned int a[4];
#pragma unroll
            for (int r = 0; r < 4; ++r) {
                const int bit = (nt & 1) * 16 + r;     // compile-time
                float s = ((wsel >> bit) & 1u) ? sc[nt][r] : -200.0f;
                a[r] = __float_as_uint(__builtin_amdgcn_exp2f(s)) + 0x8000u;
            }
            uint2 pk;
            pk.x = __builtin_amdgcn_perm(a[1], a[0], 0x07060302u);
            pk.y = __builtin_amdgcn_perm(a[3], a[2], 0x07060302u);
            *(uint2*)&Ps[wid][l15][nt * 16 + quad * 4] = pk;
        }
        // O += P V ; l += P 1   (P A-frag: row l15, contiguous tokens)
        bf16x8 ap0 = *(bf16x8*)&Ps[wid][l15][quad * 8];
        bf16x8 ap1 = *(bf16x8*)&Ps[wid][l15][32 + quad * 8];
        accl = __builtin_amdgcn_mfma_f32_16x16x32_bf16(ap0, bl, accl, 0, 0, 0);
        accl = __builtin_amdgcn_mfma_f32_16x16x32_bf16(ap1, bl, accl, 0, 0, 0);
#pragma unroll
        for (int dt = 0; dt < 4; ++dt) {
            bf16x8 bv0 = *(bf16x8*)&Vts[dt * 16 + l15][(quad ^ ksw_rd) * 8];
            bf16x8 bv1 = *(bf16x8*)&Vts[dt * 16 + l15][((quad + 4) ^ ksw_rd) * 8];
            o[dt] = __builtin_amdgcn_mfma_f32_16x16x32_bf16(ap0, bv0, o[dt], 0, 0, 0);
            o[dt] = __builtin_amdgcn_mfma_f32_16x16x32_bf16(ap1, bv1, o[dt], 0, 0, 0);
        }
    }
    // epilogue: fp32 partials; O/l C-layout rows = quad*4+r
    float* Op = Opart + (size_t)(split * H + h) * S * D;
    float* Lp = Lpart + (size_t)(split * H + h) * S;
#pragma unroll
    for (int r = 0; r < 4; ++r) {
        int row = qbase + m0 + quad * 4 + r;
        if (l15 == 0) Lp[row] = accl[r];
#pragma unroll
        for (int dt = 0; dt < 4; ++dt)
            Op[(size_t)row * D + dt * 16 + l15] = o[dt][r];
    }
}

// ---------------------------------------------------------------------------
// Output GEMM with fused K-split combine: A[row][c] = (sum_s Opart)/(sum_s L)
// normalized to bf16 during LDS staging (head = K-tile index since c=kt*64+d).
// out = A @ Wo^T + bo, fp32 into d_out. grid (8, 64), block 256.
// ---------------------------------------------------------------------------
__global__ __launch_bounds__(256) void gemm_out(const float* __restrict__ Opart,
                                                const float* __restrict__ Lpart,
                                                const bf16* __restrict__ W,
                                                const bf16* __restrict__ bias,
                                                float* __restrict__ out, int nsplit)
{
    __shared__ bf16 As[64][72];
    __shared__ bf16 Bs[64][72];
    const int tid  = threadIdx.x;
    const int wid  = tid >> 6, lane = tid & 63;
    const int quad = lane >> 4, l15 = lane & 15;
    const int nbase = blockIdx.x * 64;
    const int mbase = blockIdx.y * 64;
    const int m0 = wid * 16;
    const size_t oh = (size_t)H * S * D;

    f32x4 acc[4];
#pragma unroll
    for (int i = 0; i < 4; ++i) acc[i] = (f32x4){0.f, 0.f, 0.f, 0.f};

    for (int kt = 0; kt < E / 64; ++kt) {
        const int kb = kt * 64;
        const int h = kt;                    // head index for this K-tile
        __syncthreads();
#pragma unroll
        for (int i = 0; i < 2; ++i) {
            int slot = tid + i * 256;
            int row = slot >> 3, kg = slot & 7;
            int qrow = mbase + row;
            size_t base = ((size_t)h * S + qrow) * D + kg * 8;
            float a[8] = {0, 0, 0, 0, 0, 0, 0, 0};
            float l = 0.f;
            for (int s = 0; s < nsplit; ++s) {
                float4 p0 = *(const float4*)(Opart + (size_t)s * oh + base);
                float4 p1 = *(const float4*)(Opart + (size_t)s * oh + base + 4);
                a[0] += p0.x; a[1] += p0.y; a[2] += p0.z; a[3] += p0.w;
                a[4] += p1.x; a[5] += p1.y; a[6] += p1.z; a[7] += p1.w;
                l += Lpart[(size_t)s * H * S + (size_t)h * S + qrow];
            }
            float inv = (l > 0.f) ? 1.f / l : 0.f;
            union { bf16 hh[8]; uint4 u; } cv;
#pragma unroll
            for (int j = 0; j < 8; ++j) cv.hh[j] = (bf16)(a[j] * inv);
            *(uint4*)&As[row][kg * 8] = cv.u;
            *(uint4*)&Bs[row][kg * 8] = *(const uint4*)&W[(size_t)(nbase + row) * E + kb + kg * 8];
        }
        __syncthreads();
        bf16x8 a0 = *(bf16x8*)&As[m0 + l15][quad * 8];
        bf16x8 a1 = *(bf16x8*)&As[m0 + l15][32 + quad * 8];
#pragma unroll
        for (int nt = 0; nt < 4; ++nt) {
            bf16x8 b0 = *(bf16x8*)&Bs[nt * 16 + l15][quad * 8];
            bf16x8 b1 = *(bf16x8*)&Bs[nt * 16 + l15][32 + quad * 8];
            acc[nt] = __builtin_amdgcn_mfma_f32_16x16x32_bf16(a0, b0, acc[nt], 0, 0, 0);
            acc[nt] = __builtin_amdgcn_mfma_f32_16x16x32_bf16(a1, b1, acc[nt], 0, 0, 0);
        }
    }
#pragma unroll
    for (int nt = 0; nt < 4; ++nt) {
        int col = nbase + nt * 16 + l15;
        float bv = (float)bias[col];
#pragma unroll
        for (int r = 0; r < 4; ++r) {
            int row = mbase + m0 + quad * 4 + r;
            out[(size_t)row * E + col] = acc[nt][r] + bv;
        }
    }
}

// ---------------------------------------------------------------------------
extern "C" void kernel_launch(void* const* d_in, const int* in_sizes, int n_in,
                              void* d_out, int out_size, void* d_ws, size_t ws_size,
                              hipStream_t stream)
{
    char* ws = (char*)d_ws;
    const size_t MB = (size_t)1 << 20;
    bf16* Qw   = (bf16*)(ws + 0 * MB);        // 12 MB: Q|K|V planar cat
    bf16* Kw   = (bf16*)(ws + 4 * MB);
    bf16* Vw   = (bf16*)(ws + 8 * MB);
    unsigned long long* bitsT = (unsigned long long*)(ws + 16 * MB); // 2 MB
    bf16* xb   = (bf16*)(ws + 18 * MB);       // 4 MB
    bf16* Wcat = (bf16*)(ws + 22 * MB);       // 1.5 MB
    bf16* Wob  = (bf16*)(ws + 24 * MB);       // 0.5 MB
    bf16* bcat = (bf16*)(ws + 25 * MB);
    bf16* bob  = (bf16*)(ws + 25 * MB + 8192);
    float* Opart = (float*)(ws + 26 * MB);    // nsplit x 8 MB

    int nsplit = (ws_size >= 59 * MB) ? 4 : 2;
    int ktper  = (S / 64) / nsplit;
    float* Lpart = (float*)(ws + 26 * MB + (size_t)nsplit * 8 * MB);

    hipLaunchKernelGGL(prep, dim3(2048), dim3(256), 0, stream,
                       d_in[9], bitsT,
                       (const float*)d_in[0], (const float*)d_in[1],
                       (const float*)d_in[3], (const float*)d_in[5],
                       (const float*)d_in[7], (const float*)d_in[2],
                       (const float*)d_in[4], (const float*)d_in[6],
                       (const float*)d_in[8],
                       xb, Wcat, Wob, bcat, bob);
    hipLaunchKernelGGL(gemm_qkv, dim3(24, 64), dim3(256), 0, stream,
                       xb, Wcat, bcat, Qw);
    hipLaunchKernelGGL(attn, dim3(S / 64, H, nsplit), dim3(256), 0, stream,
                       Qw, Kw, Vw, bitsT, Opart, Lpart, ktper);
    hipLaunchKernelGGL(gemm_out, dim3(8, 64), dim3(256), 0, stream,
                       Opart, Lpart, Wob, bob, (float*)d_out, nsplit);
}